// Round 7
// baseline (360.094 us; speedup 1.0000x reference)
//
#include <hip/hip_runtime.h>
#include <hip/hip_bf16.h>

// ============================================================================
// Exact algebra (verified rounds 1-6): pos branch is rank-1 in the query index
// => pos_attn rows identical = w[b,h,j] = softmax_j(-s[b,h,j]); renorm no-op.
// out_head = (1-g)*softmax(QK^T/sqrt(dh))@V + g*(w@V).
// bf16 MFMA 32x32x16; C/D: col=lane&31, row=(reg&3)+8*(reg>>2)+4*(lane>>5).
// No-max softmax: Q pre-scaled to exp2 units, sigma(S)~1.44 => exp2 safe.
// Round 7: ONE global barrier (hand-rolled) instead of 3. W/x consumed as f32
// directly in fragment form (no prep phase); pv via co-resident flag blocks;
// out-projection folded into attention via per-(b,qb) completion counters.
// 512 blocks, launch_bounds(256,2) => co-residency guaranteed by occupancy.
// ============================================================================

constexpr int N_ = 1024, PD_ = 16;
constexpr unsigned NB_ = 512;

typedef short  s8v  __attribute__((ext_vector_type(8)));
typedef float  f16v __attribute__((ext_vector_type(16)));
typedef unsigned u4v __attribute__((ext_vector_type(4)));

__device__ inline unsigned pkbf(float lo, float hi) {
  unsigned r;
  asm("v_cvt_pk_bf16_f32 %0, %1, %2" : "=v"(r) : "v"(lo), "v"(hi));
  return r;
}
__device__ inline short bf16r(float f) {
  unsigned u = __float_as_uint(f);
  u += 0x7fff + ((u >> 16) & 1);
  return (short)(u >> 16);
}
__device__ inline float bfu(short s) {
  return __uint_as_float(((unsigned)(unsigned short)s) << 16);
}

union SMem {
  struct {
    float sWp1[256], sbp1[16], sWp2[512], sbp2[32], sWhc[32], redm[4], reds[4];
  } pos;
  struct {
    float sml[4][32];
    float sO[4][32][33];
  } attn;
  float pvred[32][9];
};

// ---- lean device-wide barrier (all NB_ blocks co-resident by construction) --
__device__ inline void gsync(unsigned* cnt, unsigned* gen) {
  __syncthreads();                    // drains this block's vmcnt (all threads)
  if (threadIdx.x == 0) {
    __threadfence();                  // wb L2 -> device-visible
    unsigned g = __hip_atomic_load(gen, __ATOMIC_ACQUIRE, __HIP_MEMORY_SCOPE_AGENT);
    unsigned old = __hip_atomic_fetch_add(cnt, 1u, __ATOMIC_ACQ_REL, __HIP_MEMORY_SCOPE_AGENT);
    if (old == NB_ - 1u) {
      __hip_atomic_store(cnt, 0u, __ATOMIC_RELAXED, __HIP_MEMORY_SCOPE_AGENT);
      __hip_atomic_fetch_add(gen, 1u, __ATOMIC_ACQ_REL, __HIP_MEMORY_SCOPE_AGENT);
    } else {
      while (__hip_atomic_load(gen, __ATOMIC_ACQUIRE, __HIP_MEMORY_SCOPE_AGENT) == g)
        __builtin_amdgcn_s_sleep(8);
    }
    __threadfence();                  // inv caches before consuming
  }
  __syncthreads();
}

// ---- phase A unit: QKV GEMM from f32 x / f32 W (fragment-direct) ------------
__device__ __forceinline__ void do_qkv(
    int u, int tid, const float* __restrict__ x,
    const float* __restrict__ Wq, const float* __restrict__ Wk,
    const float* __restrict__ Wv,
    short* __restrict__ Qb, short* __restrict__ Kb, short* __restrict__ Vtb)
{
  int w = tid >> 6, l = tid & 63, H = l >> 5, li = l & 31;
  int cb = u % 12, mb = u / 12;
  int m0 = mb * 64 + (w & 1) * 32;
  int c0 = cb * 64 + (w >> 1) * 32;       // [0,768) = 3 mats x 256 cols
  int mat = c0 >> 8, mc = c0 & 255;
  const float* W = (mat == 0) ? Wq : (mat == 1) ? Wk : Wv;
  float scale = (mat == 0) ? 0.2550348662f : 1.0f;   // log2(e)/sqrt(32)
  const float* Ap = x + (size_t)(m0 + li) * 256 + 8 * H;
  const float* Bp = W + (size_t)(8 * H) * 256 + mc + li;
  f16v acc = {};
#pragma unroll
  for (int kc = 0; kc < 16; ++kc) {
    float4 a0 = *(const float4*)(Ap + 16 * kc);
    float4 a1 = *(const float4*)(Ap + 16 * kc + 4);
    u4v ua = { pkbf(a0.x, a0.y), pkbf(a0.z, a0.w), pkbf(a1.x, a1.y), pkbf(a1.z, a1.w) };
    const float* bp = Bp + (size_t)(16 * kc) * 256;
    float b0 = bp[0]        * scale, b1 = bp[256]      * scale;
    float b2 = bp[2 * 256]  * scale, b3 = bp[3 * 256]  * scale;
    float b4 = bp[4 * 256]  * scale, b5 = bp[5 * 256]  * scale;
    float b6 = bp[6 * 256]  * scale, b7 = bp[7 * 256]  * scale;
    u4v ub = { pkbf(b0, b1), pkbf(b2, b3), pkbf(b4, b5), pkbf(b6, b7) };
    acc = __builtin_amdgcn_mfma_f32_32x32x16_bf16(
        __builtin_bit_cast(s8v, ua), __builtin_bit_cast(s8v, ub), acc, 0, 0, 0);
  }
  int h = mc >> 5;
  int b = m0 >> 10, nb = m0 & 1023;
  int bh = b * 8 + h;
  if (mat < 2) {
    short* Dst = (mat == 0) ? Qb : Kb;
#pragma unroll
    for (int r = 0; r < 16; ++r) {
      int crow = (r & 3) + 8 * (r >> 2) + 4 * H;
      Dst[((size_t)(bh * 1024 + nb + crow)) * 32 + li] = bf16r(acc[r]);
    }
  } else {
#pragma unroll
    for (int q2 = 0; q2 < 4; ++q2) {
      uint2 val = make_uint2(pkbf(acc[q2 * 4 + 0], acc[q2 * 4 + 1]),
                             pkbf(acc[q2 * 4 + 2], acc[q2 * 4 + 3]));
      *(uint2*)(Vtb + ((size_t)(bh * 32 + li)) * 1024 + nb + 8 * q2 + 4 * H) = val;
    }
  }
}

// ---- phase A unit: pos MLP + softmax -> Ww ---------------------------------
__device__ __forceinline__ void do_pos(
    int bh, int tid, SMem& sm,
    const float* __restrict__ pos, const float* __restrict__ Wp1,
    const float* __restrict__ bp1, const float* __restrict__ Wp2,
    const float* __restrict__ bp2, const float* __restrict__ Wh,
    float* __restrict__ Ww)
{
  int b = bh >> 3, h = bh & 7;
  sm.pos.sWp1[tid] = Wp1[tid];
  sm.pos.sWp2[tid] = Wp2[tid];
  sm.pos.sWp2[tid + 256] = Wp2[tid + 256];
  if (tid < 16) sm.pos.sbp1[tid] = bp1[tid];
  if (tid < 32) { sm.pos.sbp2[tid] = bp2[tid]; sm.pos.sWhc[tid] = Wh[tid * 8 + h]; }
  __syncthreads();

  float a[4];
#pragma unroll
  for (int nn = 0; nn < 4; ++nn) {
    int n = nn * 256 + tid;
    const float* prow = pos + (size_t)((b << 10) + n) * PD_;
    float pr[16];
#pragma unroll
    for (int r = 0; r < 16; ++r) pr[r] = prow[r];
    float h1[16];
#pragma unroll
    for (int c = 0; c < 16; ++c) {
      float v = sm.pos.sbp1[c];
#pragma unroll
      for (int r = 0; r < 16; ++r) v = fmaf(pr[r], sm.pos.sWp1[r * 16 + c], v);
      h1[c] = fmaxf(v, 0.0f);
    }
    float s = 0.0f;
#pragma unroll
    for (int d = 0; d < 32; ++d) {
      float v = sm.pos.sbp2[d];
#pragma unroll
      for (int c = 0; c < 16; ++c) v = fmaf(h1[c], sm.pos.sWp2[c * 32 + d], v);
      s = fmaf(v, sm.pos.sWhc[d], s);
    }
    a[nn] = -s;   // bh[h] constant over n: cancels
  }
  float m = fmaxf(fmaxf(a[0], a[1]), fmaxf(a[2], a[3]));
#pragma unroll
  for (int off = 32; off >= 1; off >>= 1) m = fmaxf(m, __shfl_xor(m, off));
  if ((tid & 63) == 0) sm.pos.redm[tid >> 6] = m;
  __syncthreads();
  float M = fmaxf(fmaxf(sm.pos.redm[0], sm.pos.redm[1]),
                  fmaxf(sm.pos.redm[2], sm.pos.redm[3]));
  float e0 = __expf(a[0] - M), e1 = __expf(a[1] - M);
  float e2 = __expf(a[2] - M), e3 = __expf(a[3] - M);
  float su = e0 + e1 + e2 + e3;
#pragma unroll
  for (int off = 32; off >= 1; off >>= 1) su += __shfl_xor(su, off);
  if ((tid & 63) == 0) sm.pos.reds[tid >> 6] = su;
  __syncthreads();
  float inv = 1.0f / (sm.pos.reds[0] + sm.pos.reds[1] + sm.pos.reds[2] + sm.pos.reds[3]);
  float* wr = Ww + (size_t)bh * N_;
  wr[tid]        = e0 * inv;
  wr[tid + 256]  = e1 * inv;
  wr[tid + 512]  = e2 * inv;
  wr[tid + 768]  = e3 * inv;
}

// ---- phase B pre-unit: pv[bh][:] = sum_n w[n] V[n][:], then flag -----------
__device__ __forceinline__ void do_pv(
    int bh, int tid, SMem& sm,
    const short* __restrict__ Vtb, const float* __restrict__ Ww,
    float* __restrict__ pv, unsigned* __restrict__ pvflag)
{
  __syncthreads();   // protect LDS union from any prior use
  int d = tid >> 3, sub = tid & 7;
  const short* Vp = Vtb + ((size_t)(bh * 32 + d)) * 1024 + sub * 128;
  const float* wp = Ww + (size_t)bh * N_ + sub * 128;
  float s = 0.0f;
  for (int nn = 0; nn < 128; nn += 8) {
    s8v v = *(const s8v*)(Vp + nn);
#pragma unroll
    for (int j = 0; j < 8; ++j) s = fmaf(wp[nn + j], bfu(v[j]), s);
  }
  sm.pvred[d][sub] = s;
  __syncthreads();
  if (tid < 32) {
    float a = 0.0f;
#pragma unroll
    for (int j = 0; j < 8; ++j) a += sm.pvred[tid][j];
    pv[bh * 32 + tid] = a;
  }
  __syncthreads();
  if (tid == 0) {
    __threadfence();
    __hip_atomic_store(&pvflag[bh], 1u, __ATOMIC_RELEASE, __HIP_MEMORY_SCOPE_AGENT);
  }
}

// ---- out tile: rows (b, qb*32..+32) x all 256 cols, Wo as f32 frags --------
__device__ __forceinline__ void do_outtile(
    int b, int qb, int tid,
    const short* __restrict__ OHhi, const short* __restrict__ OHlo,
    const float* __restrict__ Wo, const float* __restrict__ bo,
    float* __restrict__ out)
{
  int w = tid >> 6, l = tid & 63, H = l >> 5, li = l & 31;
  int m0 = b * 1024 + qb * 32;
  const short* Ah = OHhi + (size_t)(m0 + li) * 256 + 8 * H;
  const short* Al = OHlo + (size_t)(m0 + li) * 256 + 8 * H;
#pragma unroll
  for (int half = 0; half < 2; ++half) {
    int c0 = w * 32 + half * 128;
    const float* Bp = Wo + (size_t)(8 * H) * 256 + c0 + li;
    f16v acc = {};
#pragma unroll
    for (int kc = 0; kc < 16; ++kc) {
      s8v ah = *(const s8v*)(Ah + 16 * kc);
      s8v al = *(const s8v*)(Al + 16 * kc);
      const float* bp = Bp + (size_t)(16 * kc) * 256;
      float b0 = bp[0],       b1 = bp[256],     b2 = bp[2 * 256], b3 = bp[3 * 256];
      float b4 = bp[4 * 256], b5 = bp[5 * 256], b6 = bp[6 * 256], b7 = bp[7 * 256];
      u4v ub = { pkbf(b0, b1), pkbf(b2, b3), pkbf(b4, b5), pkbf(b6, b7) };
      s8v bf = __builtin_bit_cast(s8v, ub);
      acc = __builtin_amdgcn_mfma_f32_32x32x16_bf16(ah, bf, acc, 0, 0, 0);
      acc = __builtin_amdgcn_mfma_f32_32x32x16_bf16(al, bf, acc, 0, 0, 0);
    }
    float bias = bo[c0 + li];
#pragma unroll
    for (int r = 0; r < 16; ++r) {
      int crow = (r & 3) + 8 * (r >> 2) + 4 * H;
      out[(size_t)(m0 + crow) * 256 + c0 + li] = acc[r] + bias;
    }
  }
}

// ---- phase B unit: flash attn + gate + OH store + out-completion -----------
__device__ __forceinline__ void do_attn(
    int u, int tid, SMem& sm, int* s_last,
    const short* __restrict__ Qb, const short* __restrict__ Kb,
    const short* __restrict__ Vtb, float* __restrict__ pv,
    const float* __restrict__ gate,
    short* __restrict__ OHhi, short* __restrict__ OHlo,
    unsigned* __restrict__ pvflag, unsigned* __restrict__ outcnt,
    const float* __restrict__ Wo, const float* __restrict__ bo,
    float* __restrict__ out)
{
  int w = tid >> 6, l = tid & 63, H = l >> 5, li = l & 31;
  int bh = (u & 7) * 4 + (u >> 8);   // 4 bh per XCD -> K/V L2-resident
  int qb = (u >> 3) & 31;
  int n0 = qb * 32;

  const short* Qp = Qb + ((size_t)(bh * 1024 + n0 + li)) * 32 + 8 * H;
  s8v qf0 = *(const s8v*)(Qp);
  s8v qf1 = *(const s8v*)(Qp + 16);
  const short* Kbase = Kb + ((size_t)(bh * 1024)) * 32 + 8 * H;
  const short* Vbase = Vtb + ((size_t)(bh * 32 + li)) * 1024 + 8 * H;

  f16v acc = {};
  float lsum = 0.0f;

  for (int ch = 0; ch < 8; ++ch) {
    int jb = w * 256 + ch * 32;
    const short* Kp = Kbase + (size_t)(jb + li) * 32;
    s8v kf0 = *(const s8v*)(Kp);
    s8v kf1 = *(const s8v*)(Kp + 16);
    const short* Vp = Vbase + jb;
    s8v vf0 = *(const s8v*)(Vp);
    s8v vf1 = *(const s8v*)(Vp + 16);

    f16v S = {};
    S = __builtin_amdgcn_mfma_f32_32x32x16_bf16(kf0, qf0, S, 0, 0, 0);
    S = __builtin_amdgcn_mfma_f32_32x32x16_bf16(kf1, qf1, S, 0, 0, 0);

    float p[16];
#pragma unroll
    for (int r = 0; r < 16; ++r) {
      p[r] = __builtin_amdgcn_exp2f(S[r]);   // no max: sigma(S)~1.44, safe
      lsum += p[r];
    }

    unsigned a0 = pkbf(p[0], p[1]),  a1 = pkbf(p[2], p[3]);
    unsigned b0 = pkbf(p[4], p[5]),  b1 = pkbf(p[6], p[7]);
    unsigned c0 = pkbf(p[8], p[9]),  c1 = pkbf(p[10], p[11]);
    unsigned d0 = pkbf(p[12], p[13]), d1 = pkbf(p[14], p[15]);
    unsigned sa0 = __shfl_xor(a0, 32), sa1 = __shfl_xor(a1, 32);
    unsigned sb0 = __shfl_xor(b0, 32), sb1 = __shfl_xor(b1, 32);
    unsigned sc0 = __shfl_xor(c0, 32), sc1 = __shfl_xor(c1, 32);
    unsigned sd0 = __shfl_xor(d0, 32), sd1 = __shfl_xor(d1, 32);
    u4v t0 = { H ? sb0 : a0, H ? sb1 : a1, H ? b0 : sa0, H ? b1 : sa1 };
    u4v t1 = { H ? sd0 : c0, H ? sd1 : c1, H ? d0 : sc0, H ? d1 : sc1 };

    acc = __builtin_amdgcn_mfma_f32_32x32x16_bf16(vf0, __builtin_bit_cast(s8v, t0), acc, 0, 0, 0);
    acc = __builtin_amdgcn_mfma_f32_32x32x16_bf16(vf1, __builtin_bit_cast(s8v, t1), acc, 0, 0, 0);
  }

  lsum += __shfl_xor(lsum, 32);
  __syncthreads();   // protect sm union reuse
  if (H == 0) sm.attn.sml[w][li] = lsum;
#pragma unroll
  for (int r = 0; r < 16; ++r) {
    int d = (r & 3) + 8 * (r >> 2) + 4 * H;
    sm.attn.sO[w][d][li] = acc[r];
  }
  __syncthreads();

  // wait pv ready (producers are co-resident and run pv first)
  if (tid == 0) {
    while (__hip_atomic_load(&pvflag[bh], __ATOMIC_ACQUIRE, __HIP_MEMORY_SCOPE_AGENT) == 0u)
      __builtin_amdgcn_s_sleep(2);
    __threadfence();
  }
  __syncthreads();

  int i = tid >> 3, dq = (tid & 7) * 4;
  float L = sm.attn.sml[0][i] + sm.attn.sml[1][i] + sm.attn.sml[2][i] + sm.attn.sml[3][i];
  int b = bh >> 3, h = bh & 7;
  float gh = 1.0f / (1.0f + __expf(-gate[h]));
  float invL = (1.0f - gh) / L;
  float pvv[4];
#pragma unroll
  for (int q = 0; q < 4; ++q)
    pvv[q] = __hip_atomic_load(&pv[bh * 32 + dq + q], __ATOMIC_RELAXED, __HIP_MEMORY_SCOPE_AGENT);
  float o[4];
#pragma unroll
  for (int q = 0; q < 4; ++q)
    o[q] = (sm.attn.sO[0][dq + q][i] + sm.attn.sO[1][dq + q][i]
          + sm.attn.sO[2][dq + q][i] + sm.attn.sO[3][dq + q][i]) * invL + gh * pvv[q];
  float hi[4], lo[4];
#pragma unroll
  for (int q = 0; q < 4; ++q) {
    hi[q] = bfu(bf16r(o[q]));
    lo[q] = o[q] - hi[q];
  }
  size_t off = ((size_t)(b * 1024 + n0 + i)) * 256 + h * 32 + dq;
  *(uint2*)(OHhi + off) = make_uint2(pkbf(hi[0], hi[1]), pkbf(hi[2], hi[3]));
  *(uint2*)(OHlo + off) = make_uint2(pkbf(lo[0], lo[1]), pkbf(lo[2], lo[3]));

  // completion counter for (b,qb): 8th head-finisher computes the out tile
  __syncthreads();   // drains OH stores (vmcnt) for all threads
  if (tid == 0) {
    __threadfence();
    unsigned idx = (unsigned)(b * 32 + qb);
    bool lastv = (__hip_atomic_fetch_add(&outcnt[idx], 1u, __ATOMIC_ACQ_REL,
                                         __HIP_MEMORY_SCOPE_AGENT) == 7u);
    if (lastv) __threadfence();
    *s_last = lastv ? 1 : 0;
  }
  __syncthreads();
  if (*s_last) do_outtile(b, qb, tid, OHhi, OHlo, Wo, bo, out);
}

// ---- the megakernel --------------------------------------------------------
__global__ __launch_bounds__(256, 2) void k_mega(
    const float* __restrict__ x, const float* __restrict__ pos,
    const float* __restrict__ Wq, const float* __restrict__ Wk,
    const float* __restrict__ Wv, const float* __restrict__ Wo,
    const float* __restrict__ bo, const float* __restrict__ Wp1,
    const float* __restrict__ bp1, const float* __restrict__ Wp2,
    const float* __restrict__ bp2, const float* __restrict__ Wh,
    const float* __restrict__ gate, float* __restrict__ out,
    short* __restrict__ Qb, short* __restrict__ Kb, short* __restrict__ Vtb,
    short* __restrict__ OHhi, short* __restrict__ OHlo,
    float* __restrict__ Ww, float* __restrict__ pv, unsigned* __restrict__ ctrl)
{
  __shared__ SMem sm;
  __shared__ int s_last;
  int bid = blockIdx.x, tid = threadIdx.x;
  unsigned* cnt    = ctrl;
  unsigned* gen    = ctrl + 1;
  unsigned* pvflag = ctrl + 16;    // [32]
  unsigned* outcnt = ctrl + 64;    // [128]

  // ---------------- phase A: QKV (768 units) + pos (32 units) --------------
  for (int u = bid; u < 800; u += NB_) {
    if (u < 768) do_qkv(u, tid, x, Wq, Wk, Wv, Qb, Kb, Vtb);
    else         do_pos(u - 768, tid, sm, pos, Wp1, bp1, Wp2, bp2, Wh, Ww);
  }

  gsync(cnt, gen);

  // ---------------- phase B: pv producers first, then attn+out -------------
  for (int u = bid; u < 1024; u += NB_)
    if (((u >> 3) & 31) == 0)
      do_pv((u & 7) * 4 + (u >> 8), tid, sm, Vtb, Ww, pv, pvflag);

  for (int u = bid; u < 1024; u += NB_)
    do_attn(u, tid, sm, &s_last, Qb, Kb, Vtb, pv, gate, OHhi, OHlo,
            pvflag, outcnt, Wo, bo, out);
}

// ============================================================================
extern "C" void kernel_launch(void* const* d_in, const int* in_sizes, int n_in,
                              void* d_out, int out_size, void* d_ws, size_t ws_size,
                              hipStream_t stream) {
  const float* x    = (const float*)d_in[0];
  // d_in[1] = deep_semantics: unused by the reference
  const float* pos  = (const float*)d_in[2];
  const float* Wq   = (const float*)d_in[3];
  const float* Wk   = (const float*)d_in[4];
  const float* Wv   = (const float*)d_in[5];
  const float* Wo   = (const float*)d_in[6];
  const float* bo   = (const float*)d_in[7];
  const float* Wp1  = (const float*)d_in[8];
  const float* bp1  = (const float*)d_in[9];
  const float* Wp2  = (const float*)d_in[10];
  const float* bp2  = (const float*)d_in[11];
  const float* Wh   = (const float*)d_in[12];
  // d_in[13] = bh: cancels in softmax over keys
  const float* gate = (const float*)d_in[14];
  float* out = (float*)d_out;

  char* base = (char*)d_ws;
  short*    Qb   = (short*)(base);                               // 2MB
  short*    Kb   = (short*)(base + (2u << 20));                  // 2MB
  short*    Vtb  = (short*)(base + (4u << 20));                  // 2MB [bh][d][n]
  short*    OHhi = (short*)(base + (6u << 20));                  // 2MB
  short*    OHlo = (short*)(base + (8u << 20));                  // 2MB
  float*    Ww   = (float*)(base + (10u << 20));                 // 128KB
  float*    pv   = (float*)(base + (10u << 20) + (128u << 10));  // 4KB
  unsigned* ctrl = (unsigned*)(base + (10u << 20) + (132u << 10)); // 4KB

  // zero barrier/flag words each launch (capture-legal memset node)
  hipMemsetAsync(ctrl, 0, 1024, stream);

  void* args[] = {
    (void*)&x, (void*)&pos, (void*)&Wq, (void*)&Wk, (void*)&Wv, (void*)&Wo,
    (void*)&bo, (void*)&Wp1, (void*)&bp1, (void*)&Wp2, (void*)&bp2, (void*)&Wh,
    (void*)&gate, (void*)&out, (void*)&Qb, (void*)&Kb, (void*)&Vtb,
    (void*)&OHhi, (void*)&OHlo, (void*)&Ww, (void*)&pv, (void*)&ctrl
  };
  hipError_t lerr = hipLaunchCooperativeKernel((void*)k_mega, dim3(NB_),
                                               dim3(256), args, 0, stream);
  if (lerr != hipSuccess) {
    // occupancy-identical plain launch (co-residency still guaranteed by
    // launch_bounds(256,2): 512 blocks = 2/CU x 256 CU)
    k_mega<<<dim3(NB_), dim3(256), 0, stream>>>(
        x, pos, Wq, Wk, Wv, Wo, bo, Wp1, bp1, Wp2, bp2, Wh, gate, out,
        Qb, Kb, Vtb, OHhi, OHlo, Ww, pv, ctrl);
  }
}

// Round 8
// 99.295 us; speedup vs baseline: 3.6265x; 3.6265x over previous
//
#include <hip/hip_runtime.h>
#include <hip/hip_bf16.h>

// ============================================================================
// Round 8: MEASUREMENT ROUND. Byte-identical to round 4 (57.7us anchor) plus
// THREE duplicate k_attn dispatches into scratch buffers. dur8 - 64.6 ~= 3*T_attn.
// (Round 7 lesson: hand-rolled agent-scope barriers/fences cause L2-writeback
// storms on 8-XCD gfx950 — WRITE_SIZE 18MB->182MB, 6x slowdown. Reverted.)
// Exact algebra (verified rounds 1-6): pos branch is rank-1 in query index =>
// pos_attn rows identical = w[b,h,j] = softmax_j(-s[b,h,j]); renorm no-op.
// ============================================================================

constexpr int N_ = 1024, PD_ = 16;

typedef short  s8v  __attribute__((ext_vector_type(8)));
typedef float  f16v __attribute__((ext_vector_type(16)));
typedef unsigned u4v __attribute__((ext_vector_type(4)));

__device__ inline unsigned pkbf(float lo, float hi) {
  unsigned r;
  asm("v_cvt_pk_bf16_f32 %0, %1, %2" : "=v"(r) : "v"(lo), "v"(hi));
  return r;
}
__device__ inline short bf16r(float f) {
  unsigned u = __float_as_uint(f);
  u += 0x7fff + ((u >> 16) & 1);
  return (short)(u >> 16);
}
__device__ inline float bfu(short s) {
  return __uint_as_float(((unsigned)(unsigned short)s) << 16);
}

// ---- K1: W^T->bf16 (64 blk) | pos MLP+softmax + pv zero (32 blk) |
//          x->bf16 (512 blk) --------------------------------------------------
__global__ __launch_bounds__(256) void k_prep(
    const float* __restrict__ Wq, const float* __restrict__ Wk,
    const float* __restrict__ Wv, const float* __restrict__ Wo,
    const float* __restrict__ pos, const float* __restrict__ Wp1,
    const float* __restrict__ bp1, const float* __restrict__ Wp2,
    const float* __restrict__ bp2, const float* __restrict__ Wh,
    const float* __restrict__ x,
    short* __restrict__ Wt, short* __restrict__ Wot, float* __restrict__ Ww,
    short* __restrict__ xb, float* __restrict__ pv)
{
  int bid = blockIdx.x;
  int tid = threadIdx.x;

  if (bid >= 96) {
    size_t idx = ((size_t)(bid - 96) * 256 + tid) * 8;
    const float4* p = (const float4*)(x + idx);
    float4 f0 = p[0], f1 = p[1];
    u4v o = { pkbf(f0.x, f0.y), pkbf(f0.z, f0.w), pkbf(f1.x, f1.y), pkbf(f1.z, f1.w) };
    *(u4v*)(xb + idx) = o;
    return;
  }

  if (bid < 64) {
    __shared__ float tile[64][65];
    int mat = bid >> 4, t = bid & 15;
    int k0 = (t >> 2) * 64, c0 = (t & 3) * 64;
    const float* W = mat == 0 ? Wq : mat == 1 ? Wk : mat == 2 ? Wv : Wo;
    float scale = (mat == 0) ? 0.2550348662f : 1.0f;   // log2(e)/sqrt(32)
#pragma unroll
    for (int i = 0; i < 16; ++i) {
      int e = tid + i * 256;
      int kr = e >> 6, cc = e & 63;
      tile[kr][cc] = W[(size_t)(k0 + kr) * 256 + c0 + cc];
    }
    __syncthreads();
    short* dst = (mat == 3) ? Wot : (Wt + mat * 65536);
#pragma unroll
    for (int i = 0; i < 16; ++i) {
      int e = tid + i * 256;
      int cr = e >> 6, kk = e & 63;
      dst[(size_t)(c0 + cr) * 256 + k0 + kk] = bf16r(tile[kk][cr] * scale);
    }
    return;
  }

  __shared__ float sWp1[256], sbp1[16], sWp2[512], sbp2[32], sWhc[32];
  __shared__ float redm[4], reds[4];
  int bh = bid - 64;
  int b = bh >> 3, h = bh & 7;
  if (tid < 32) pv[bh * 32 + tid] = 0.0f;
  sWp1[tid] = Wp1[tid];
  sWp2[tid] = Wp2[tid];
  sWp2[tid + 256] = Wp2[tid + 256];
  if (tid < 16) sbp1[tid] = bp1[tid];
  if (tid < 32) { sbp2[tid] = bp2[tid]; sWhc[tid] = Wh[tid * 8 + h]; }
  __syncthreads();

  float a[4];
#pragma unroll
  for (int nn = 0; nn < 4; ++nn) {
    int n = nn * 256 + tid;
    const float* prow = pos + (size_t)((b << 10) + n) * PD_;
    float pr[16];
#pragma unroll
    for (int r = 0; r < 16; ++r) pr[r] = prow[r];
    float h1[16];
#pragma unroll
    for (int c = 0; c < 16; ++c) {
      float v = sbp1[c];
#pragma unroll
      for (int r = 0; r < 16; ++r) v = fmaf(pr[r], sWp1[r * 16 + c], v);
      h1[c] = fmaxf(v, 0.0f);
    }
    float s = 0.0f;
#pragma unroll
    for (int d = 0; d < 32; ++d) {
      float v = sbp2[d];
#pragma unroll
      for (int c = 0; c < 16; ++c) v = fmaf(h1[c], sWp2[c * 32 + d], v);
      s = fmaf(v, sWhc[d], s);
    }
    a[nn] = -s;   // bh[h] constant over n: cancels
  }
  float m = fmaxf(fmaxf(a[0], a[1]), fmaxf(a[2], a[3]));
#pragma unroll
  for (int off = 32; off >= 1; off >>= 1) m = fmaxf(m, __shfl_xor(m, off));
  if ((tid & 63) == 0) redm[tid >> 6] = m;
  __syncthreads();
  float M = fmaxf(fmaxf(redm[0], redm[1]), fmaxf(redm[2], redm[3]));
  float e0 = __expf(a[0] - M), e1 = __expf(a[1] - M);
  float e2 = __expf(a[2] - M), e3 = __expf(a[3] - M);
  float su = e0 + e1 + e2 + e3;
#pragma unroll
  for (int off = 32; off >= 1; off >>= 1) su += __shfl_xor(su, off);
  if ((tid & 63) == 0) reds[tid >> 6] = su;
  __syncthreads();
  float inv = 1.0f / (reds[0] + reds[1] + reds[2] + reds[3]);
  float* wr = Ww + (size_t)bh * N_;
  wr[tid]        = e0 * inv;
  wr[tid + 256]  = e1 * inv;
  wr[tid + 512]  = e2 * inv;
  wr[tid + 768]  = e3 * inv;
}

// ---- K2: QKV GEMM (bf16), 32x32/wave; V-epilogue accumulates pv ------------
__global__ __launch_bounds__(256) void k_qkv(
    const short* __restrict__ xb, const short* __restrict__ Wt,
    const float* __restrict__ Ww,
    short* __restrict__ Qb, short* __restrict__ Kb, short* __restrict__ Vtb,
    float* __restrict__ pv)
{
  int tid = threadIdx.x;
  int w = tid >> 6, l = tid & 63, H = l >> 5, li = l & 31;
  int bid = blockIdx.x;
  int cb = bid % 12, mb = bid / 12;
  int m0 = mb * 64 + (w & 1) * 32;
  int c0 = cb * 64 + (w >> 1) * 32;
  const short* Ap = xb + (size_t)(m0 + li) * 256 + 8 * H;
  const short* Bp = Wt + (size_t)(c0 + li) * 256 + 8 * H;
  f16v acc = {};
#pragma unroll
  for (int kc = 0; kc < 16; ++kc) {
    s8v af = *(const s8v*)(Ap + 16 * kc);
    s8v bf = *(const s8v*)(Bp + 16 * kc);
    acc = __builtin_amdgcn_mfma_f32_32x32x16_bf16(af, bf, acc, 0, 0, 0);
  }
  int mat = c0 >> 8, mc = c0 & 255;
  int h = mc >> 5;
  int b = m0 >> 10, nb = m0 & 1023;
  int bh = b * 8 + h;
  if (mat < 2) {
    short* Dst = (mat == 0) ? Qb : Kb;
#pragma unroll
    for (int r = 0; r < 16; ++r) {
      int crow = (r & 3) + 8 * (r >> 2) + 4 * H;
      Dst[((size_t)(bh * 1024 + nb + crow)) * 32 + li] = bf16r(acc[r]);
    }
  } else {
#pragma unroll
    for (int q2 = 0; q2 < 4; ++q2) {
      uint2 val = make_uint2(pkbf(acc[q2 * 4 + 0], acc[q2 * 4 + 1]),
                             pkbf(acc[q2 * 4 + 2], acc[q2 * 4 + 3]));
      *(uint2*)(Vtb + ((size_t)(bh * 32 + li)) * 1024 + nb + 8 * q2 + 4 * H) = val;
    }
    const float* wp = Ww + (size_t)bh * N_ + nb;
    float part = 0.0f;
#pragma unroll
    for (int r = 0; r < 16; ++r) {
      int crow = (r & 3) + 8 * (r >> 2) + 4 * H;
      part = fmaf(wp[crow], acc[r], part);
    }
    atomicAdd(&pv[bh * 32 + li], part);
  }
}

// ---- K3: flash attn (no-max exp2), split-bf16 OH ----------------------------
__global__ __launch_bounds__(256) void k_attn(
    const short* __restrict__ Qb, const short* __restrict__ Kb,
    const short* __restrict__ Vtb, const float* __restrict__ pv,
    const float* __restrict__ gate,
    short* __restrict__ OHhi, short* __restrict__ OHlo)
{
  __shared__ float sml[4][32];
  __shared__ float sO[4][32][33];
  int tid = threadIdx.x;
  int w = tid >> 6, l = tid & 63, H = l >> 5, li = l & 31;
  int bid = blockIdx.x;
  int bh = (bid & 7) * 4 + (bid >> 8);   // 4 bh per XCD -> K/V L2-resident
  int qb = (bid >> 3) & 31;
  int n0 = qb * 32;

  const short* Qp = Qb + ((size_t)(bh * 1024 + n0 + li)) * 32 + 8 * H;
  s8v qf0 = *(const s8v*)(Qp);
  s8v qf1 = *(const s8v*)(Qp + 16);
  const short* Kbase = Kb + ((size_t)(bh * 1024)) * 32 + 8 * H;
  const short* Vbase = Vtb + ((size_t)(bh * 32 + li)) * 1024 + 8 * H;

  f16v acc = {};
  float lsum = 0.0f;

#pragma unroll 2
  for (int ch = 0; ch < 8; ++ch) {
    int jb = w * 256 + ch * 32;
    const short* Kp = Kbase + (size_t)(jb + li) * 32;
    s8v kf0 = *(const s8v*)(Kp);
    s8v kf1 = *(const s8v*)(Kp + 16);
    const short* Vp = Vbase + jb;
    s8v vf0 = *(const s8v*)(Vp);
    s8v vf1 = *(const s8v*)(Vp + 16);

    f16v S = {};
    S = __builtin_amdgcn_mfma_f32_32x32x16_bf16(kf0, qf0, S, 0, 0, 0);
    S = __builtin_amdgcn_mfma_f32_32x32x16_bf16(kf1, qf1, S, 0, 0, 0);

    float p[16];
#pragma unroll
    for (int r = 0; r < 16; ++r) {
      p[r] = __builtin_amdgcn_exp2f(S[r]);   // no max: sigma(S)~1.44, safe
      lsum += p[r];
    }

    unsigned a0 = pkbf(p[0], p[1]),  a1 = pkbf(p[2], p[3]);
    unsigned b0 = pkbf(p[4], p[5]),  b1 = pkbf(p[6], p[7]);
    unsigned c0 = pkbf(p[8], p[9]),  c1 = pkbf(p[10], p[11]);
    unsigned d0 = pkbf(p[12], p[13]), d1 = pkbf(p[14], p[15]);
    unsigned sa0 = __shfl_xor(a0, 32), sa1 = __shfl_xor(a1, 32);
    unsigned sb0 = __shfl_xor(b0, 32), sb1 = __shfl_xor(b1, 32);
    unsigned sc0 = __shfl_xor(c0, 32), sc1 = __shfl_xor(c1, 32);
    unsigned sd0 = __shfl_xor(d0, 32), sd1 = __shfl_xor(d1, 32);
    u4v t0 = { H ? sb0 : a0, H ? sb1 : a1, H ? b0 : sa0, H ? b1 : sa1 };
    u4v t1 = { H ? sd0 : c0, H ? sd1 : c1, H ? d0 : sc0, H ? d1 : sc1 };

    acc = __builtin_amdgcn_mfma_f32_32x32x16_bf16(vf0, __builtin_bit_cast(s8v, t0), acc, 0, 0, 0);
    acc = __builtin_amdgcn_mfma_f32_32x32x16_bf16(vf1, __builtin_bit_cast(s8v, t1), acc, 0, 0, 0);
  }

  lsum += __shfl_xor(lsum, 32);
  if (H == 0) sml[w][li] = lsum;
#pragma unroll
  for (int r = 0; r < 16; ++r) {
    int d = (r & 3) + 8 * (r >> 2) + 4 * H;
    sO[w][d][li] = acc[r];
  }
  __syncthreads();

  int i = tid >> 3, dq = (tid & 7) * 4;
  float L = sml[0][i] + sml[1][i] + sml[2][i] + sml[3][i];
  int b = bh >> 3, h = bh & 7;
  float gh = 1.0f / (1.0f + __expf(-gate[h]));
  float invL = (1.0f - gh) / L;
  const float4 pvv = *(const float4*)(pv + bh * 32 + dq);
  float o[4] = {
    (sO[0][dq + 0][i] + sO[1][dq + 0][i] + sO[2][dq + 0][i] + sO[3][dq + 0][i]) * invL + gh * pvv.x,
    (sO[0][dq + 1][i] + sO[1][dq + 1][i] + sO[2][dq + 1][i] + sO[3][dq + 1][i]) * invL + gh * pvv.y,
    (sO[0][dq + 2][i] + sO[1][dq + 2][i] + sO[2][dq + 2][i] + sO[3][dq + 2][i]) * invL + gh * pvv.z,
    (sO[0][dq + 3][i] + sO[1][dq + 3][i] + sO[2][dq + 3][i] + sO[3][dq + 3][i]) * invL + gh * pvv.w
  };
  float hi[4], lo[4];
#pragma unroll
  for (int q = 0; q < 4; ++q) {
    hi[q] = bfu(bf16r(o[q]));
    lo[q] = o[q] - hi[q];
  }
  size_t off = ((size_t)(b * 1024 + n0 + i)) * 256 + h * 32 + dq;
  *(uint2*)(OHhi + off) = make_uint2(pkbf(hi[0], hi[1]), pkbf(hi[2], hi[3]));
  *(uint2*)(OHlo + off) = make_uint2(pkbf(lo[0], lo[1]), pkbf(lo[2], lo[3]));
}

// ---- K4: out = (OHhi+OHlo) @ Wo + bo ----------------------------------------
__global__ __launch_bounds__(256) void k_out(
    const short* __restrict__ OHhi, const short* __restrict__ OHlo,
    const short* __restrict__ Wot, const float* __restrict__ bo,
    float* __restrict__ out)
{
  int tid = threadIdx.x;
  int w = tid >> 6, l = tid & 63, H = l >> 5, li = l & 31;
  int bid = blockIdx.x;
  int m0 = (bid >> 2) * 64 + (w & 1) * 32;
  int c0 = (bid & 3) * 64 + (w >> 1) * 32;
  const short* Ah = OHhi + (size_t)(m0 + li) * 256 + 8 * H;
  const short* Al = OHlo + (size_t)(m0 + li) * 256 + 8 * H;
  const short* Bp = Wot + (size_t)(c0 + li) * 256 + 8 * H;
  f16v acc = {};
#pragma unroll
  for (int kc = 0; kc < 16; ++kc) {
    s8v bf = *(const s8v*)(Bp + 16 * kc);
    s8v ah = *(const s8v*)(Ah + 16 * kc);
    s8v al = *(const s8v*)(Al + 16 * kc);
    acc = __builtin_amdgcn_mfma_f32_32x32x16_bf16(ah, bf, acc, 0, 0, 0);
    acc = __builtin_amdgcn_mfma_f32_32x32x16_bf16(al, bf, acc, 0, 0, 0);
  }
  float bias = bo[c0 + li];
#pragma unroll
  for (int r = 0; r < 16; ++r) {
    int crow = (r & 3) + 8 * (r >> 2) + 4 * H;
    out[(size_t)(m0 + crow) * 256 + c0 + li] = acc[r] + bias;
  }
}

// ============================================================================
extern "C" void kernel_launch(void* const* d_in, const int* in_sizes, int n_in,
                              void* d_out, int out_size, void* d_ws, size_t ws_size,
                              hipStream_t stream) {
  const float* x    = (const float*)d_in[0];
  // d_in[1] = deep_semantics: unused by the reference
  const float* pos  = (const float*)d_in[2];
  const float* Wq   = (const float*)d_in[3];
  const float* Wk   = (const float*)d_in[4];
  const float* Wv   = (const float*)d_in[5];
  const float* Wo   = (const float*)d_in[6];
  const float* bo   = (const float*)d_in[7];
  const float* Wp1  = (const float*)d_in[8];
  const float* bp1  = (const float*)d_in[9];
  const float* Wp2  = (const float*)d_in[10];
  const float* bp2  = (const float*)d_in[11];
  const float* Wh   = (const float*)d_in[12];
  // d_in[13] = bh: cancels in softmax over keys
  const float* gate = (const float*)d_in[14];
  float* out = (float*)d_out;

  char* base = (char*)d_ws;
  short* Qb    = (short*)(base);                               // 2MB
  short* Kb    = (short*)(base + (2u << 20));                  // 2MB
  short* Vtb   = (short*)(base + (4u << 20));                  // 2MB [bh][d][n]
  short* OHhi  = (short*)(base + (6u << 20));                  // 2MB
  short* OHlo  = (short*)(base + (8u << 20));                  // 2MB
  short* xb    = (short*)(base + (10u << 20));                 // 2MB
  short* Wt    = (short*)(base + (12u << 20));                 // 384KB
  short* Wot   = (short*)(base + (12u << 20) + (384u << 10));  // 128KB
  float* Ww    = (float*)(base + (12u << 20) + (512u << 10));  // 128KB
  float* pv    = (float*)(base + (12u << 20) + (640u << 10));  // 4KB
  short* OHhi2 = (short*)(base + (16u << 20));                 // scratch 2MB
  short* OHlo2 = (short*)(base + (18u << 20));                 // scratch 2MB

  k_prep<<<608,  256, 0, stream>>>(Wq, Wk, Wv, Wo, pos, Wp1, bp1, Wp2, bp2, Wh,
                                   x, Wt, Wot, Ww, xb, pv);
  k_qkv <<<768,  256, 0, stream>>>(xb, Wt, Ww, Qb, Kb, Vtb, pv);
  k_attn<<<1024, 256, 0, stream>>>(Qb, Kb, Vtb, pv, gate, OHhi, OHlo);
  // --- amplification probe: 3 duplicate attn dispatches into scratch ---
  k_attn<<<1024, 256, 0, stream>>>(Qb, Kb, Vtb, pv, gate, OHhi2, OHlo2);
  k_attn<<<1024, 256, 0, stream>>>(Qb, Kb, Vtb, pv, gate, OHhi2, OHlo2);
  k_attn<<<1024, 256, 0, stream>>>(Qb, Kb, Vtb, pv, gate, OHhi2, OHlo2);
  k_out <<<256,  256, 0, stream>>>(OHhi, OHlo, Wot, bo, out);
}

// Round 10
// 59.145 us; speedup vs baseline: 6.0884x; 1.6788x over previous
//
#include <hip/hip_runtime.h>
#include <hip/hip_bf16.h>

// ============================================================================
// Round 10: consolidation after two failed experiments (r9 NaN was in the new
// co-launched pv/pvWo blocks; reverted). All bodies below are byte-identical
// to bodies that passed in earlier rounds:
//   k_prep pos/Wo-prep  = r4 (pass)        k_qkv fragment-direct = r7 (pass)
//   k_qkv pv epilogue   = r4 (pass)        k_attn, k_out        = r4/r8 (pass)
// Changes vs r4 (57.7us): x-cvt pass deleted (qkv reads f32 x directly),
// W staging deleted (qkv packs f32 W in-register), k_prep 608->48 blocks.
// Exact algebra (verified r1-r8): pos branch is rank-1 in query index =>
// pos_attn rows identical = w[b,h,j] = softmax_j(-s[b,h,j]); renorm no-op.
// bf16 MFMA 32x32x16; C/D: col=lane&31, row=(reg&3)+8*(reg>>2)+4*(lane>>5).
// No-max softmax: Wq pre-scaled to exp2 units (sigma(S)~1.44, safe).
// ============================================================================

constexpr int N_ = 1024, PD_ = 16;

typedef short  s8v  __attribute__((ext_vector_type(8)));
typedef float  f16v __attribute__((ext_vector_type(16)));
typedef unsigned u4v __attribute__((ext_vector_type(4)));

__device__ inline unsigned pkbf(float lo, float hi) {
  unsigned r;
  asm("v_cvt_pk_bf16_f32 %0, %1, %2" : "=v"(r) : "v"(lo), "v"(hi));
  return r;
}
__device__ inline short bf16r(float f) {
  unsigned u = __float_as_uint(f);
  u += 0x7fff + ((u >> 16) & 1);
  return (short)(u >> 16);
}
__device__ inline float bfu(short s) {
  return __uint_as_float(((unsigned)(unsigned short)s) << 16);
}

// ---- K1: pos MLP+softmax + pv zero (32 blk) | Wo^T->bf16 (16 blk) ----------
__global__ __launch_bounds__(256) void k_prep(
    const float* __restrict__ pos, const float* __restrict__ Wp1,
    const float* __restrict__ bp1, const float* __restrict__ Wp2,
    const float* __restrict__ bp2, const float* __restrict__ Wh,
    const float* __restrict__ Wo,
    float* __restrict__ Ww, short* __restrict__ Wot, float* __restrict__ pv)
{
  int bid = blockIdx.x;
  int tid = threadIdx.x;

  if (bid >= 32) {
    // ---- Wo^T -> bf16 tile (r4-verified body, scale=1) ----
    __shared__ float tile[64][65];
    int t = bid - 32;
    int k0 = (t >> 2) * 64, c0 = (t & 3) * 64;
#pragma unroll
    for (int i = 0; i < 16; ++i) {
      int e = tid + i * 256;
      int kr = e >> 6, cc = e & 63;
      tile[kr][cc] = Wo[(size_t)(k0 + kr) * 256 + c0 + cc];
    }
    __syncthreads();
#pragma unroll
    for (int i = 0; i < 16; ++i) {
      int e = tid + i * 256;
      int cr = e >> 6, kk = e & 63;
      Wot[(size_t)(c0 + cr) * 256 + k0 + kk] = bf16r(tile[kk][cr]);
    }
    return;
  }

  // ---- pos branch (r4-verified body): one block per (b,h), 4 n's/thread ----
  __shared__ float sWp1[256], sbp1[16], sWp2[512], sbp2[32], sWhc[32];
  __shared__ float redm[4], reds[4];
  int bh = bid;
  int b = bh >> 3, h = bh & 7;
  if (tid < 32) pv[bh * 32 + tid] = 0.0f;   // zero pv for k_qkv's atomics
  sWp1[tid] = Wp1[tid];
  sWp2[tid] = Wp2[tid];
  sWp2[tid + 256] = Wp2[tid + 256];
  if (tid < 16) sbp1[tid] = bp1[tid];
  if (tid < 32) { sbp2[tid] = bp2[tid]; sWhc[tid] = Wh[tid * 8 + h]; }
  __syncthreads();

  float a[4];
#pragma unroll
  for (int nn = 0; nn < 4; ++nn) {
    int n = nn * 256 + tid;
    const float* prow = pos + (size_t)((b << 10) + n) * PD_;
    float pr[16];
#pragma unroll
    for (int r = 0; r < 16; ++r) pr[r] = prow[r];
    float h1[16];
#pragma unroll
    for (int c = 0; c < 16; ++c) {
      float v = sbp1[c];
#pragma unroll
      for (int r = 0; r < 16; ++r) v = fmaf(pr[r], sWp1[r * 16 + c], v);
      h1[c] = fmaxf(v, 0.0f);
    }
    float s = 0.0f;
#pragma unroll
    for (int d = 0; d < 32; ++d) {
      float v = sbp2[d];
#pragma unroll
      for (int c = 0; c < 16; ++c) v = fmaf(h1[c], sWp2[c * 32 + d], v);
      s = fmaf(v, sWhc[d], s);
    }
    a[nn] = -s;   // bh[h] constant over n: cancels
  }
  float m = fmaxf(fmaxf(a[0], a[1]), fmaxf(a[2], a[3]));
#pragma unroll
  for (int off = 32; off >= 1; off >>= 1) m = fmaxf(m, __shfl_xor(m, off));
  if ((tid & 63) == 0) redm[tid >> 6] = m;
  __syncthreads();
  float M = fmaxf(fmaxf(redm[0], redm[1]), fmaxf(redm[2], redm[3]));
  float e0 = __expf(a[0] - M), e1 = __expf(a[1] - M);
  float e2 = __expf(a[2] - M), e3 = __expf(a[3] - M);
  float su = e0 + e1 + e2 + e3;
#pragma unroll
  for (int off = 32; off >= 1; off >>= 1) su += __shfl_xor(su, off);
  if ((tid & 63) == 0) reds[tid >> 6] = su;
  __syncthreads();
  float inv = 1.0f / (reds[0] + reds[1] + reds[2] + reds[3]);
  float* wr = Ww + (size_t)bh * N_;
  wr[tid]        = e0 * inv;
  wr[tid + 256]  = e1 * inv;
  wr[tid + 512]  = e2 * inv;
  wr[tid + 768]  = e3 * inv;
}

// ---- K2: QKV GEMM fragment-direct from f32 (r7-verified) + pv atomics ------
__global__ __launch_bounds__(256) void k_qkv(
    const float* __restrict__ x, const float* __restrict__ Wq,
    const float* __restrict__ Wk, const float* __restrict__ Wv,
    const float* __restrict__ Ww,
    short* __restrict__ Qb, short* __restrict__ Kb, short* __restrict__ Vtb,
    float* __restrict__ pv)
{
  int tid = threadIdx.x;
  int w = tid >> 6, l = tid & 63, H = l >> 5, li = l & 31;
  int u = blockIdx.x;
  int cb = u % 12, mb = u / 12;
  int m0 = mb * 64 + (w & 1) * 32;
  int c0 = cb * 64 + (w >> 1) * 32;       // [0,768) = 3 mats x 256 cols
  int mat = c0 >> 8, mc = c0 & 255;
  const float* W = (mat == 0) ? Wq : (mat == 1) ? Wk : Wv;
  float scale = (mat == 0) ? 0.2550348662f : 1.0f;   // log2(e)/sqrt(32)
  const float* Ap = x + (size_t)(m0 + li) * 256 + 8 * H;
  const float* Bp = W + (size_t)(8 * H) * 256 + mc + li;
  f16v acc = {};
#pragma unroll
  for (int kc = 0; kc < 16; ++kc) {
    float4 a0 = *(const float4*)(Ap + 16 * kc);
    float4 a1 = *(const float4*)(Ap + 16 * kc + 4);
    u4v ua = { pkbf(a0.x, a0.y), pkbf(a0.z, a0.w), pkbf(a1.x, a1.y), pkbf(a1.z, a1.w) };
    const float* bp = Bp + (size_t)(16 * kc) * 256;
    float b0 = bp[0]        * scale, b1 = bp[256]      * scale;
    float b2 = bp[2 * 256]  * scale, b3 = bp[3 * 256]  * scale;
    float b4 = bp[4 * 256]  * scale, b5 = bp[5 * 256]  * scale;
    float b6 = bp[6 * 256]  * scale, b7 = bp[7 * 256]  * scale;
    u4v ub = { pkbf(b0, b1), pkbf(b2, b3), pkbf(b4, b5), pkbf(b6, b7) };
    acc = __builtin_amdgcn_mfma_f32_32x32x16_bf16(
        __builtin_bit_cast(s8v, ua), __builtin_bit_cast(s8v, ub), acc, 0, 0, 0);
  }
  int h = mc >> 5;
  int b = m0 >> 10, nb = m0 & 1023;
  int bh = b * 8 + h;
  if (mat < 2) {
    short* Dst = (mat == 0) ? Qb : Kb;
#pragma unroll
    for (int r = 0; r < 16; ++r) {
      int crow = (r & 3) + 8 * (r >> 2) + 4 * H;
      Dst[((size_t)(bh * 1024 + nb + crow)) * 32 + li] = bf16r(acc[r]);
    }
  } else {
#pragma unroll
    for (int q2 = 0; q2 < 4; ++q2) {
      uint2 val = make_uint2(pkbf(acc[q2 * 4 + 0], acc[q2 * 4 + 1]),
                             pkbf(acc[q2 * 4 + 2], acc[q2 * 4 + 3]));
      *(uint2*)(Vtb + ((size_t)(bh * 32 + li)) * 1024 + nb + 8 * q2 + 4 * H) = val;
    }
    // pv partial from the f32 accumulators already in registers (r4-verified)
    const float* wp = Ww + (size_t)bh * N_ + nb;
    float part = 0.0f;
#pragma unroll
    for (int r = 0; r < 16; ++r) {
      int crow = (r & 3) + 8 * (r >> 2) + 4 * H;
      part = fmaf(wp[crow], acc[r], part);
    }
    atomicAdd(&pv[bh * 32 + li], part);
  }
}

// ---- K3: flash attn (no-max exp2), split-bf16 OH (r4-verified) -------------
__global__ __launch_bounds__(256) void k_attn(
    const short* __restrict__ Qb, const short* __restrict__ Kb,
    const short* __restrict__ Vtb, const float* __restrict__ pv,
    const float* __restrict__ gate,
    short* __restrict__ OHhi, short* __restrict__ OHlo)
{
  __shared__ float sml[4][32];
  __shared__ float sO[4][32][33];
  int tid = threadIdx.x;
  int w = tid >> 6, l = tid & 63, H = l >> 5, li = l & 31;
  int bid = blockIdx.x;
  int bh = (bid & 7) * 4 + (bid >> 8);   // 4 bh per XCD -> K/V L2-resident
  int qb = (bid >> 3) & 31;
  int n0 = qb * 32;

  const short* Qp = Qb + ((size_t)(bh * 1024 + n0 + li)) * 32 + 8 * H;
  s8v qf0 = *(const s8v*)(Qp);
  s8v qf1 = *(const s8v*)(Qp + 16);
  const short* Kbase = Kb + ((size_t)(bh * 1024)) * 32 + 8 * H;
  const short* Vbase = Vtb + ((size_t)(bh * 32 + li)) * 1024 + 8 * H;

  f16v acc = {};
  float lsum = 0.0f;

#pragma unroll 2
  for (int ch = 0; ch < 8; ++ch) {
    int jb = w * 256 + ch * 32;
    const short* Kp = Kbase + (size_t)(jb + li) * 32;
    s8v kf0 = *(const s8v*)(Kp);
    s8v kf1 = *(const s8v*)(Kp + 16);
    const short* Vp = Vbase + jb;
    s8v vf0 = *(const s8v*)(Vp);
    s8v vf1 = *(const s8v*)(Vp + 16);

    f16v S = {};
    S = __builtin_amdgcn_mfma_f32_32x32x16_bf16(kf0, qf0, S, 0, 0, 0);
    S = __builtin_amdgcn_mfma_f32_32x32x16_bf16(kf1, qf1, S, 0, 0, 0);

    float p[16];
#pragma unroll
    for (int r = 0; r < 16; ++r) {
      p[r] = __builtin_amdgcn_exp2f(S[r]);   // no max: sigma(S)~1.44, safe
      lsum += p[r];
    }

    unsigned a0 = pkbf(p[0], p[1]),  a1 = pkbf(p[2], p[3]);
    unsigned b0 = pkbf(p[4], p[5]),  b1 = pkbf(p[6], p[7]);
    unsigned c0 = pkbf(p[8], p[9]),  c1 = pkbf(p[10], p[11]);
    unsigned d0 = pkbf(p[12], p[13]), d1 = pkbf(p[14], p[15]);
    unsigned sa0 = __shfl_xor(a0, 32), sa1 = __shfl_xor(a1, 32);
    unsigned sb0 = __shfl_xor(b0, 32), sb1 = __shfl_xor(b1, 32);
    unsigned sc0 = __shfl_xor(c0, 32), sc1 = __shfl_xor(c1, 32);
    unsigned sd0 = __shfl_xor(d0, 32), sd1 = __shfl_xor(d1, 32);
    u4v t0 = { H ? sb0 : a0, H ? sb1 : a1, H ? b0 : sa0, H ? b1 : sa1 };
    u4v t1 = { H ? sd0 : c0, H ? sd1 : c1, H ? d0 : sc0, H ? d1 : sc1 };

    acc = __builtin_amdgcn_mfma_f32_32x32x16_bf16(vf0, __builtin_bit_cast(s8v, t0), acc, 0, 0, 0);
    acc = __builtin_amdgcn_mfma_f32_32x32x16_bf16(vf1, __builtin_bit_cast(s8v, t1), acc, 0, 0, 0);
  }

  lsum += __shfl_xor(lsum, 32);
  if (H == 0) sml[w][li] = lsum;
#pragma unroll
  for (int r = 0; r < 16; ++r) {
    int d = (r & 3) + 8 * (r >> 2) + 4 * H;
    sO[w][d][li] = acc[r];
  }
  __syncthreads();

  int i = tid >> 3, dq = (tid & 7) * 4;
  float L = sml[0][i] + sml[1][i] + sml[2][i] + sml[3][i];
  int b = bh >> 3, h = bh & 7;
  float gh = 1.0f / (1.0f + __expf(-gate[h]));
  float invL = (1.0f - gh) / L;
  const float4 pvv = *(const float4*)(pv + bh * 32 + dq);
  float o[4] = {
    (sO[0][dq + 0][i] + sO[1][dq + 0][i] + sO[2][dq + 0][i] + sO[3][dq + 0][i]) * invL + gh * pvv.x,
    (sO[0][dq + 1][i] + sO[1][dq + 1][i] + sO[2][dq + 1][i] + sO[3][dq + 1][i]) * invL + gh * pvv.y,
    (sO[0][dq + 2][i] + sO[1][dq + 2][i] + sO[2][dq + 2][i] + sO[3][dq + 2][i]) * invL + gh * pvv.z,
    (sO[0][dq + 3][i] + sO[1][dq + 3][i] + sO[2][dq + 3][i] + sO[3][dq + 3][i]) * invL + gh * pvv.w
  };
  float hi[4], lo[4];
#pragma unroll
  for (int q = 0; q < 4; ++q) {
    hi[q] = bfu(bf16r(o[q]));
    lo[q] = o[q] - hi[q];
  }
  size_t off = ((size_t)(b * 1024 + n0 + i)) * 256 + h * 32 + dq;
  *(uint2*)(OHhi + off) = make_uint2(pkbf(hi[0], hi[1]), pkbf(hi[2], hi[3]));
  *(uint2*)(OHlo + off) = make_uint2(pkbf(lo[0], lo[1]), pkbf(lo[2], lo[3]));
}

// ---- K4: out = (OHhi+OHlo) @ Wo + bo (r4-verified) -------------------------
__global__ __launch_bounds__(256) void k_out(
    const short* __restrict__ OHhi, const short* __restrict__ OHlo,
    const short* __restrict__ Wot, const float* __restrict__ bo,
    float* __restrict__ out)
{
  int tid = threadIdx.x;
  int w = tid >> 6, l = tid & 63, H = l >> 5, li = l & 31;
  int bid = blockIdx.x;
  int m0 = (bid >> 2) * 64 + (w & 1) * 32;
  int c0 = (bid & 3) * 64 + (w >> 1) * 32;
  const short* Ah = OHhi + (size_t)(m0 + li) * 256 + 8 * H;
  const short* Al = OHlo + (size_t)(m0 + li) * 256 + 8 * H;
  const short* Bp = Wot + (size_t)(c0 + li) * 256 + 8 * H;
  f16v acc = {};
#pragma unroll
  for (int kc = 0; kc < 16; ++kc) {
    s8v bf = *(const s8v*)(Bp + 16 * kc);
    s8v ah = *(const s8v*)(Ah + 16 * kc);
    s8v al = *(const s8v*)(Al + 16 * kc);
    acc = __builtin_amdgcn_mfma_f32_32x32x16_bf16(ah, bf, acc, 0, 0, 0);
    acc = __builtin_amdgcn_mfma_f32_32x32x16_bf16(al, bf, acc, 0, 0, 0);
  }
  float bias = bo[c0 + li];
#pragma unroll
  for (int r = 0; r < 16; ++r) {
    int crow = (r & 3) + 8 * (r >> 2) + 4 * H;
    out[(size_t)(m0 + crow) * 256 + c0 + li] = acc[r] + bias;
  }
}

// ============================================================================
extern "C" void kernel_launch(void* const* d_in, const int* in_sizes, int n_in,
                              void* d_out, int out_size, void* d_ws, size_t ws_size,
                              hipStream_t stream) {
  const float* x    = (const float*)d_in[0];
  // d_in[1] = deep_semantics: unused by the reference
  const float* pos  = (const float*)d_in[2];
  const float* Wq   = (const float*)d_in[3];
  const float* Wk   = (const float*)d_in[4];
  const float* Wv   = (const float*)d_in[5];
  const float* Wo   = (const float*)d_in[6];
  const float* bo   = (const float*)d_in[7];
  const float* Wp1  = (const float*)d_in[8];
  const float* bp1  = (const float*)d_in[9];
  const float* Wp2  = (const float*)d_in[10];
  const float* bp2  = (const float*)d_in[11];
  const float* Wh   = (const float*)d_in[12];
  // d_in[13] = bh: cancels in softmax over keys
  const float* gate = (const float*)d_in[14];
  float* out = (float*)d_out;

  char* base = (char*)d_ws;
  short* Qb   = (short*)(base);                               // 2MB
  short* Kb   = (short*)(base + (2u << 20));                  // 2MB
  short* Vtb  = (short*)(base + (4u << 20));                  // 2MB [bh][d][n]
  short* OHhi = (short*)(base + (6u << 20));                  // 2MB
  short* OHlo = (short*)(base + (8u << 20));                  // 2MB
  short* Wot  = (short*)(base + (10u << 20));                 // 128KB
  float* Ww   = (float*)(base + (10u << 20) + (128u << 10));  // 128KB
  float* pv   = (float*)(base + (10u << 20) + (256u << 10));  // 4KB

  k_prep<<<48,   256, 0, stream>>>(pos, Wp1, bp1, Wp2, bp2, Wh, Wo,
                                   Ww, Wot, pv);
  k_qkv <<<768,  256, 0, stream>>>(x, Wq, Wk, Wv, Ww, Qb, Kb, Vtb, pv);
  k_attn<<<1024, 256, 0, stream>>>(Qb, Kb, Vtb, pv, gate, OHhi, OHlo);
  k_out <<<256,  256, 0, stream>>>(OHhi, OHlo, Wot, bo, out);
}

// Round 12
// 57.737 us; speedup vs baseline: 6.2368x; 1.0244x over previous
//
#include <hip/hip_runtime.h>
#include <hip/hip_bf16.h>

// ============================================================================
// Round 12: r4/r8-exact bodies everywhere EXCEPT k_attn, which keeps its
// chunk body byte-identical but moves to 8 waves/block x 128 keys/wave
// (512 threads, 4 chunks/wave, 8-way LDS combine). Halves the per-wave
// dependent chain; attacks the measured latency exposure (Occupancy ~20%,
// busy ~2us vs 11.6us marginal).
// Exact algebra (verified r1-r8): pos branch rank-1 => pos_attn rows equal
// w[b,h,j] = softmax_j(-s[b,h,j]); renorm no-op.
// bf16 MFMA 32x32x16; C/D: col=lane&31, row=(reg&3)+8*(reg>>2)+4*(lane>>5).
// No-max softmax: Wq pre-scaled to exp2 units (sigma(S)~1.44, safe).
// ============================================================================

constexpr int N_ = 1024, PD_ = 16;

typedef short  s8v  __attribute__((ext_vector_type(8)));
typedef float  f16v __attribute__((ext_vector_type(16)));
typedef unsigned u4v __attribute__((ext_vector_type(4)));

__device__ inline unsigned pkbf(float lo, float hi) {
  unsigned r;
  asm("v_cvt_pk_bf16_f32 %0, %1, %2" : "=v"(r) : "v"(lo), "v"(hi));
  return r;
}
__device__ inline short bf16r(float f) {
  unsigned u = __float_as_uint(f);
  u += 0x7fff + ((u >> 16) & 1);
  return (short)(u >> 16);
}
__device__ inline float bfu(short s) {
  return __uint_as_float(((unsigned)(unsigned short)s) << 16);
}

// ---- K1: W^T->bf16 (64 blk) | pos MLP+softmax + pv zero (32 blk) |
//          x->bf16 (512 blk)  [r4/r8-exact] ----------------------------------
__global__ __launch_bounds__(256) void k_prep(
    const float* __restrict__ Wq, const float* __restrict__ Wk,
    const float* __restrict__ Wv, const float* __restrict__ Wo,
    const float* __restrict__ pos, const float* __restrict__ Wp1,
    const float* __restrict__ bp1, const float* __restrict__ Wp2,
    const float* __restrict__ bp2, const float* __restrict__ Wh,
    const float* __restrict__ x,
    short* __restrict__ Wt, short* __restrict__ Wot, float* __restrict__ Ww,
    short* __restrict__ xb, float* __restrict__ pv)
{
  int bid = blockIdx.x;
  int tid = threadIdx.x;

  if (bid >= 96) {
    size_t idx = ((size_t)(bid - 96) * 256 + tid) * 8;
    const float4* p = (const float4*)(x + idx);
    float4 f0 = p[0], f1 = p[1];
    u4v o = { pkbf(f0.x, f0.y), pkbf(f0.z, f0.w), pkbf(f1.x, f1.y), pkbf(f1.z, f1.w) };
    *(u4v*)(xb + idx) = o;
    return;
  }

  if (bid < 64) {
    __shared__ float tile[64][65];
    int mat = bid >> 4, t = bid & 15;
    int k0 = (t >> 2) * 64, c0 = (t & 3) * 64;
    const float* W = mat == 0 ? Wq : mat == 1 ? Wk : mat == 2 ? Wv : Wo;
    float scale = (mat == 0) ? 0.2550348662f : 1.0f;   // log2(e)/sqrt(32)
#pragma unroll
    for (int i = 0; i < 16; ++i) {
      int e = tid + i * 256;
      int kr = e >> 6, cc = e & 63;
      tile[kr][cc] = W[(size_t)(k0 + kr) * 256 + c0 + cc];
    }
    __syncthreads();
    short* dst = (mat == 3) ? Wot : (Wt + mat * 65536);
#pragma unroll
    for (int i = 0; i < 16; ++i) {
      int e = tid + i * 256;
      int cr = e >> 6, kk = e & 63;
      dst[(size_t)(c0 + cr) * 256 + k0 + kk] = bf16r(tile[kk][cr] * scale);
    }
    return;
  }

  __shared__ float sWp1[256], sbp1[16], sWp2[512], sbp2[32], sWhc[32];
  __shared__ float redm[4], reds[4];
  int bh = bid - 64;
  int b = bh >> 3, h = bh & 7;
  if (tid < 32) pv[bh * 32 + tid] = 0.0f;
  sWp1[tid] = Wp1[tid];
  sWp2[tid] = Wp2[tid];
  sWp2[tid + 256] = Wp2[tid + 256];
  if (tid < 16) sbp1[tid] = bp1[tid];
  if (tid < 32) { sbp2[tid] = bp2[tid]; sWhc[tid] = Wh[tid * 8 + h]; }
  __syncthreads();

  float a[4];
#pragma unroll
  for (int nn = 0; nn < 4; ++nn) {
    int n = nn * 256 + tid;
    const float* prow = pos + (size_t)((b << 10) + n) * PD_;
    float pr[16];
#pragma unroll
    for (int r = 0; r < 16; ++r) pr[r] = prow[r];
    float h1[16];
#pragma unroll
    for (int c = 0; c < 16; ++c) {
      float v = sbp1[c];
#pragma unroll
      for (int r = 0; r < 16; ++r) v = fmaf(pr[r], sWp1[r * 16 + c], v);
      h1[c] = fmaxf(v, 0.0f);
    }
    float s = 0.0f;
#pragma unroll
    for (int d = 0; d < 32; ++d) {
      float v = sbp2[d];
#pragma unroll
      for (int c = 0; c < 16; ++c) v = fmaf(h1[c], sWp2[c * 32 + d], v);
      s = fmaf(v, sWhc[d], s);
    }
    a[nn] = -s;   // bh[h] constant over n: cancels
  }
  float m = fmaxf(fmaxf(a[0], a[1]), fmaxf(a[2], a[3]));
#pragma unroll
  for (int off = 32; off >= 1; off >>= 1) m = fmaxf(m, __shfl_xor(m, off));
  if ((tid & 63) == 0) redm[tid >> 6] = m;
  __syncthreads();
  float M = fmaxf(fmaxf(redm[0], redm[1]), fmaxf(redm[2], redm[3]));
  float e0 = __expf(a[0] - M), e1 = __expf(a[1] - M);
  float e2 = __expf(a[2] - M), e3 = __expf(a[3] - M);
  float su = e0 + e1 + e2 + e3;
#pragma unroll
  for (int off = 32; off >= 1; off >>= 1) su += __shfl_xor(su, off);
  if ((tid & 63) == 0) reds[tid >> 6] = su;
  __syncthreads();
  float inv = 1.0f / (reds[0] + reds[1] + reds[2] + reds[3]);
  float* wr = Ww + (size_t)bh * N_;
  wr[tid]        = e0 * inv;
  wr[tid + 256]  = e1 * inv;
  wr[tid + 512]  = e2 * inv;
  wr[tid + 768]  = e3 * inv;
}

// ---- K2: QKV GEMM (bf16 staged), 32x32/wave; V-epilogue pv atomics
//          [r4/r8-exact] ------------------------------------------------------
__global__ __launch_bounds__(256) void k_qkv(
    const short* __restrict__ xb, const short* __restrict__ Wt,
    const float* __restrict__ Ww,
    short* __restrict__ Qb, short* __restrict__ Kb, short* __restrict__ Vtb,
    float* __restrict__ pv)
{
  int tid = threadIdx.x;
  int w = tid >> 6, l = tid & 63, H = l >> 5, li = l & 31;
  int bid = blockIdx.x;
  int cb = bid % 12, mb = bid / 12;
  int m0 = mb * 64 + (w & 1) * 32;
  int c0 = cb * 64 + (w >> 1) * 32;
  const short* Ap = xb + (size_t)(m0 + li) * 256 + 8 * H;
  const short* Bp = Wt + (size_t)(c0 + li) * 256 + 8 * H;
  f16v acc = {};
#pragma unroll
  for (int kc = 0; kc < 16; ++kc) {
    s8v af = *(const s8v*)(Ap + 16 * kc);
    s8v bf = *(const s8v*)(Bp + 16 * kc);
    acc = __builtin_amdgcn_mfma_f32_32x32x16_bf16(af, bf, acc, 0, 0, 0);
  }
  int mat = c0 >> 8, mc = c0 & 255;
  int h = mc >> 5;
  int b = m0 >> 10, nb = m0 & 1023;
  int bh = b * 8 + h;
  if (mat < 2) {
    short* Dst = (mat == 0) ? Qb : Kb;
#pragma unroll
    for (int r = 0; r < 16; ++r) {
      int crow = (r & 3) + 8 * (r >> 2) + 4 * H;
      Dst[((size_t)(bh * 1024 + nb + crow)) * 32 + li] = bf16r(acc[r]);
    }
  } else {
#pragma unroll
    for (int q2 = 0; q2 < 4; ++q2) {
      uint2 val = make_uint2(pkbf(acc[q2 * 4 + 0], acc[q2 * 4 + 1]),
                             pkbf(acc[q2 * 4 + 2], acc[q2 * 4 + 3]));
      *(uint2*)(Vtb + ((size_t)(bh * 32 + li)) * 1024 + nb + 8 * q2 + 4 * H) = val;
    }
    const float* wp = Ww + (size_t)bh * N_ + nb;
    float part = 0.0f;
#pragma unroll
    for (int r = 0; r < 16; ++r) {
      int crow = (r & 3) + 8 * (r >> 2) + 4 * H;
      part = fmaf(wp[crow], acc[r], part);
    }
    atomicAdd(&pv[bh * 32 + li], part);
  }
}

// ---- K3: flash attn, 8 waves x 128 keys (chunk body byte-frozen) -----------
__global__ __launch_bounds__(512) void k_attn(
    const short* __restrict__ Qb, const short* __restrict__ Kb,
    const short* __restrict__ Vtb, const float* __restrict__ pv,
    const float* __restrict__ gate,
    short* __restrict__ OHhi, short* __restrict__ OHlo)
{
  __shared__ float sml[8][32];
  __shared__ float sO[8][32][33];
  int tid = threadIdx.x;
  int w = tid >> 6, l = tid & 63, H = l >> 5, li = l & 31;   // w in 0..7
  int bid = blockIdx.x;
  int bh = (bid & 7) * 4 + (bid >> 8);   // 4 bh per XCD -> K/V L2-resident
  int qb = (bid >> 3) & 31;
  int n0 = qb * 32;

  const short* Qp = Qb + ((size_t)(bh * 1024 + n0 + li)) * 32 + 8 * H;
  s8v qf0 = *(const s8v*)(Qp);
  s8v qf1 = *(const s8v*)(Qp + 16);
  const short* Kbase = Kb + ((size_t)(bh * 1024)) * 32 + 8 * H;
  const short* Vbase = Vtb + ((size_t)(bh * 32 + li)) * 1024 + 8 * H;

  f16v acc = {};
  float lsum = 0.0f;

#pragma unroll 2
  for (int ch = 0; ch < 4; ++ch) {
    int jb = w * 128 + ch * 32;
    const short* Kp = Kbase + (size_t)(jb + li) * 32;
    s8v kf0 = *(const s8v*)(Kp);
    s8v kf1 = *(const s8v*)(Kp + 16);
    const short* Vp = Vbase + jb;
    s8v vf0 = *(const s8v*)(Vp);
    s8v vf1 = *(const s8v*)(Vp + 16);

    f16v S = {};
    S = __builtin_amdgcn_mfma_f32_32x32x16_bf16(kf0, qf0, S, 0, 0, 0);
    S = __builtin_amdgcn_mfma_f32_32x32x16_bf16(kf1, qf1, S, 0, 0, 0);

    float p[16];
#pragma unroll
    for (int r = 0; r < 16; ++r) {
      p[r] = __builtin_amdgcn_exp2f(S[r]);   // no max: sigma(S)~1.44, safe
      lsum += p[r];
    }

    unsigned a0 = pkbf(p[0], p[1]),  a1 = pkbf(p[2], p[3]);
    unsigned b0 = pkbf(p[4], p[5]),  b1 = pkbf(p[6], p[7]);
    unsigned c0 = pkbf(p[8], p[9]),  c1 = pkbf(p[10], p[11]);
    unsigned d0 = pkbf(p[12], p[13]), d1 = pkbf(p[14], p[15]);
    unsigned sa0 = __shfl_xor(a0, 32), sa1 = __shfl_xor(a1, 32);
    unsigned sb0 = __shfl_xor(b0, 32), sb1 = __shfl_xor(b1, 32);
    unsigned sc0 = __shfl_xor(c0, 32), sc1 = __shfl_xor(c1, 32);
    unsigned sd0 = __shfl_xor(d0, 32), sd1 = __shfl_xor(d1, 32);
    u4v t0 = { H ? sb0 : a0, H ? sb1 : a1, H ? b0 : sa0, H ? b1 : sa1 };
    u4v t1 = { H ? sd0 : c0, H ? sd1 : c1, H ? d0 : sc0, H ? d1 : sc1 };

    acc = __builtin_amdgcn_mfma_f32_32x32x16_bf16(vf0, __builtin_bit_cast(s8v, t0), acc, 0, 0, 0);
    acc = __builtin_amdgcn_mfma_f32_32x32x16_bf16(vf1, __builtin_bit_cast(s8v, t1), acc, 0, 0, 0);
  }

  lsum += __shfl_xor(lsum, 32);
  if (H == 0) sml[w][li] = lsum;
#pragma unroll
  for (int r = 0; r < 16; ++r) {
    int d = (r & 3) + 8 * (r >> 2) + 4 * H;
    sO[w][d][li] = acc[r];
  }
  __syncthreads();

  if (tid < 256) {
    int i = tid >> 3, dq = (tid & 7) * 4;
    float L = sml[0][i] + sml[1][i] + sml[2][i] + sml[3][i]
            + sml[4][i] + sml[5][i] + sml[6][i] + sml[7][i];
    int b = bh >> 3, h = bh & 7;
    float gh = 1.0f / (1.0f + __expf(-gate[h]));
    float invL = (1.0f - gh) / L;
    const float4 pvv = *(const float4*)(pv + bh * 32 + dq);
    float o[4];
#pragma unroll
    for (int q = 0; q < 4; ++q) {
      o[q] = (sO[0][dq + q][i] + sO[1][dq + q][i] + sO[2][dq + q][i] + sO[3][dq + q][i]
            + sO[4][dq + q][i] + sO[5][dq + q][i] + sO[6][dq + q][i] + sO[7][dq + q][i]) * invL;
    }
    o[0] += gh * pvv.x; o[1] += gh * pvv.y; o[2] += gh * pvv.z; o[3] += gh * pvv.w;
    float hi[4], lo[4];
#pragma unroll
    for (int q = 0; q < 4; ++q) {
      hi[q] = bfu(bf16r(o[q]));
      lo[q] = o[q] - hi[q];
    }
    size_t off = ((size_t)(b * 1024 + n0 + i)) * 256 + h * 32 + dq;
    *(uint2*)(OHhi + off) = make_uint2(pkbf(hi[0], hi[1]), pkbf(hi[2], hi[3]));
    *(uint2*)(OHlo + off) = make_uint2(pkbf(lo[0], lo[1]), pkbf(lo[2], lo[3]));
  }
}

// ---- K4: out = (OHhi+OHlo) @ Wo + bo  [r4/r8-exact] -------------------------
__global__ __launch_bounds__(256) void k_out(
    const short* __restrict__ OHhi, const short* __restrict__ OHlo,
    const short* __restrict__ Wot, const float* __restrict__ bo,
    float* __restrict__ out)
{
  int tid = threadIdx.x;
  int w = tid >> 6, l = tid & 63, H = l >> 5, li = l & 31;
  int bid = blockIdx.x;
  int m0 = (bid >> 2) * 64 + (w & 1) * 32;
  int c0 = (bid & 3) * 64 + (w >> 1) * 32;
  const short* Ah = OHhi + (size_t)(m0 + li) * 256 + 8 * H;
  const short* Al = OHlo + (size_t)(m0 + li) * 256 + 8 * H;
  const short* Bp = Wot + (size_t)(c0 + li) * 256 + 8 * H;
  f16v acc = {};
#pragma unroll
  for (int kc = 0; kc < 16; ++kc) {
    s8v bf = *(const s8v*)(Bp + 16 * kc);
    s8v ah = *(const s8v*)(Ah + 16 * kc);
    s8v al = *(const s8v*)(Al + 16 * kc);
    acc = __builtin_amdgcn_mfma_f32_32x32x16_bf16(ah, bf, acc, 0, 0, 0);
    acc = __builtin_amdgcn_mfma_f32_32x32x16_bf16(al, bf, acc, 0, 0, 0);
  }
  float bias = bo[c0 + li];
#pragma unroll
  for (int r = 0; r < 16; ++r) {
    int crow = (r & 3) + 8 * (r >> 2) + 4 * H;
    out[(size_t)(m0 + crow) * 256 + c0 + li] = acc[r] + bias;
  }
}

// ============================================================================
extern "C" void kernel_launch(void* const* d_in, const int* in_sizes, int n_in,
                              void* d_out, int out_size, void* d_ws, size_t ws_size,
                              hipStream_t stream) {
  const float* x    = (const float*)d_in[0];
  // d_in[1] = deep_semantics: unused by the reference
  const float* pos  = (const float*)d_in[2];
  const float* Wq   = (const float*)d_in[3];
  const float* Wk   = (const float*)d_in[4];
  const float* Wv   = (const float*)d_in[5];
  const float* Wo   = (const float*)d_in[6];
  const float* bo   = (const float*)d_in[7];
  const float* Wp1  = (const float*)d_in[8];
  const float* bp1  = (const float*)d_in[9];
  const float* Wp2  = (const float*)d_in[10];
  const float* bp2  = (const float*)d_in[11];
  const float* Wh   = (const float*)d_in[12];
  // d_in[13] = bh: cancels in softmax over keys
  const float* gate = (const float*)d_in[14];
  float* out = (float*)d_out;

  char* base = (char*)d_ws;
  short* Qb   = (short*)(base);                               // 2MB
  short* Kb   = (short*)(base + (2u << 20));                  // 2MB
  short* Vtb  = (short*)(base + (4u << 20));                  // 2MB [bh][d][n]
  short* OHhi = (short*)(base + (6u << 20));                  // 2MB
  short* OHlo = (short*)(base + (8u << 20));                  // 2MB
  short* xb   = (short*)(base + (10u << 20));                 // 2MB
  short* Wt   = (short*)(base + (12u << 20));                 // 384KB
  short* Wot  = (short*)(base + (12u << 20) + (384u << 10));  // 128KB
  float* Ww   = (float*)(base + (12u << 20) + (512u << 10));  // 128KB
  float* pv   = (float*)(base + (12u << 20) + (640u << 10));  // 4KB

  k_prep<<<608,  256, 0, stream>>>(Wq, Wk, Wv, Wo, pos, Wp1, bp1, Wp2, bp2, Wh,
                                   x, Wt, Wot, Ww, xb, pv);
  k_qkv <<<768,  256, 0, stream>>>(xb, Wt, Ww, Qb, Kb, Vtb, pv);
  k_attn<<<1024, 512, 0, stream>>>(Qb, Kb, Vtb, pv, gate, OHhi, OHlo);
  k_out <<<256,  256, 0, stream>>>(OHhi, OHlo, Wot, bo, out);
}

// Round 13
// 43.943 us; speedup vs baseline: 8.1945x; 1.3139x over previous
//
#include <hip/hip_runtime.h>
#include <hip/hip_bf16.h>

// ============================================================================
// Round 13: FRAGMENT-MAJOR LAYOUTS. Same math as r4/r8/r12 (all frozen);
// every staged tensor is stored so MFMA operand loads are contiguous 2KB
// wave transactions instead of 64-lane gathers at 64-2048B stride.
//   X/Q/K/W/OH: [tile][kc][row&31][16]  addr=((tile*16+kc)*32+row&31)*16+(k&15)
//   V:          [bh][ks][s][d][H][8]    addr=(((bh*32+ks)*2+s)*32+d)*16+H*8+jj
// Exact algebra (r1-r8): pos branch rank-1 => w[b,h,j]=softmax_j(-s[b,h,j]);
// renorm no-op. bf16 MFMA 32x32x16; C/D col=lane&31, row=(reg&3)+8*(reg>>2)
// +4*(lane>>5). No-max softmax: Wq pre-scaled to exp2 units (sigma~1.44).
// ============================================================================

constexpr int N_ = 1024, PD_ = 16;

typedef short  s8v  __attribute__((ext_vector_type(8)));
typedef float  f16v __attribute__((ext_vector_type(16)));
typedef unsigned u4v __attribute__((ext_vector_type(4)));

__device__ inline unsigned pkbf(float lo, float hi) {
  unsigned r;
  asm("v_cvt_pk_bf16_f32 %0, %1, %2" : "=v"(r) : "v"(lo), "v"(hi));
  return r;
}
__device__ inline short bf16r(float f) {
  unsigned u = __float_as_uint(f);
  u += 0x7fff + ((u >> 16) & 1);
  return (short)(u >> 16);
}
__device__ inline float bfu(short s) {
  return __uint_as_float(((unsigned)(unsigned short)s) << 16);
}

// ---- K1: W^T->frag-major (64 blk) | pos MLP+softmax + pv zero (32 blk) |
//          x->frag-major bf16 (512 blk) --------------------------------------
__global__ __launch_bounds__(256) void k_prep(
    const float* __restrict__ Wq, const float* __restrict__ Wk,
    const float* __restrict__ Wv, const float* __restrict__ Wo,
    const float* __restrict__ pos, const float* __restrict__ Wp1,
    const float* __restrict__ bp1, const float* __restrict__ Wp2,
    const float* __restrict__ bp2, const float* __restrict__ Wh,
    const float* __restrict__ x,
    short* __restrict__ Wtf, short* __restrict__ Wof, float* __restrict__ Ww,
    short* __restrict__ xf, float* __restrict__ pv)
{
  int bid = blockIdx.x;
  int tid = threadIdx.x;

  if (bid >= 96) {
    // ---- x -> bf16 fragment-major, 8 consecutive k per thread ----
    size_t idx = ((size_t)(bid - 96) * 256 + tid) * 8;
    int m = (int)(idx >> 8), k0 = (int)(idx & 255);
    const float4* p = (const float4*)(x + idx);
    float4 f0 = p[0], f1 = p[1];
    u4v o = { pkbf(f0.x, f0.y), pkbf(f0.z, f0.w), pkbf(f1.x, f1.y), pkbf(f1.z, f1.w) };
    size_t dst = ((size_t)((m >> 5) * 16 + (k0 >> 4))) * 512 + (m & 31) * 16 + (k0 & 15);
    *(u4v*)(xf + dst) = o;
    return;
  }

  if (bid < 64) {
    // ---- W transpose + bf16 -> fragment-major over (c,k) ----
    __shared__ float tile[64][65];
    int mat = bid >> 4, t = bid & 15;
    int k0t = (t >> 2) * 64, c0t = (t & 3) * 64;
    const float* W = mat == 0 ? Wq : mat == 1 ? Wk : mat == 2 ? Wv : Wo;
    float scale = (mat == 0) ? 0.2550348662f : 1.0f;   // log2(e)/sqrt(32)
#pragma unroll
    for (int i = 0; i < 16; ++i) {
      int e = tid + i * 256;
      int kr = e >> 6, cc = e & 63;
      tile[kr][cc] = W[(size_t)(k0t + kr) * 256 + c0t + cc];
    }
    __syncthreads();
    short* dst = (mat == 3) ? Wof : (Wtf + mat * 65536);
#pragma unroll
    for (int i = 0; i < 16; ++i) {
      int e = tid + i * 256;
      int cr = e >> 6, kk = e & 63;
      int c = c0t + cr, k = k0t + kk;
      size_t a = ((size_t)((c >> 5) * 16 + (k >> 4))) * 512 + (c & 31) * 16 + (k & 15);
      dst[a] = bf16r(tile[kk][cr] * scale);
    }
    return;
  }

  // ---- pos branch (frozen): one block per (b,h), 4 n's/thread ----
  __shared__ float sWp1[256], sbp1[16], sWp2[512], sbp2[32], sWhc[32];
  __shared__ float redm[4], reds[4];
  int bh = bid - 64;
  int b = bh >> 3, h = bh & 7;
  if (tid < 32) pv[bh * 32 + tid] = 0.0f;
  sWp1[tid] = Wp1[tid];
  sWp2[tid] = Wp2[tid];
  sWp2[tid + 256] = Wp2[tid + 256];
  if (tid < 16) sbp1[tid] = bp1[tid];
  if (tid < 32) { sbp2[tid] = bp2[tid]; sWhc[tid] = Wh[tid * 8 + h]; }
  __syncthreads();

  float a[4];
#pragma unroll
  for (int nn = 0; nn < 4; ++nn) {
    int n = nn * 256 + tid;
    const float* prow = pos + (size_t)((b << 10) + n) * PD_;
    float pr[16];
#pragma unroll
    for (int r = 0; r < 16; ++r) pr[r] = prow[r];
    float h1[16];
#pragma unroll
    for (int c = 0; c < 16; ++c) {
      float v = sbp1[c];
#pragma unroll
      for (int r = 0; r < 16; ++r) v = fmaf(pr[r], sWp1[r * 16 + c], v);
      h1[c] = fmaxf(v, 0.0f);
    }
    float s = 0.0f;
#pragma unroll
    for (int d = 0; d < 32; ++d) {
      float v = sbp2[d];
#pragma unroll
      for (int c = 0; c < 16; ++c) v = fmaf(h1[c], sWp2[c * 32 + d], v);
      s = fmaf(v, sWhc[d], s);
    }
    a[nn] = -s;   // bh[h] constant over n: cancels
  }
  float m = fmaxf(fmaxf(a[0], a[1]), fmaxf(a[2], a[3]));
#pragma unroll
  for (int off = 32; off >= 1; off >>= 1) m = fmaxf(m, __shfl_xor(m, off));
  if ((tid & 63) == 0) redm[tid >> 6] = m;
  __syncthreads();
  float M = fmaxf(fmaxf(redm[0], redm[1]), fmaxf(redm[2], redm[3]));
  float e0 = __expf(a[0] - M), e1 = __expf(a[1] - M);
  float e2 = __expf(a[2] - M), e3 = __expf(a[3] - M);
  float su = e0 + e1 + e2 + e3;
#pragma unroll
  for (int off = 32; off >= 1; off >>= 1) su += __shfl_xor(su, off);
  if ((tid & 63) == 0) reds[tid >> 6] = su;
  __syncthreads();
  float inv = 1.0f / (reds[0] + reds[1] + reds[2] + reds[3]);
  float* wr = Ww + (size_t)bh * N_;
  wr[tid]        = e0 * inv;
  wr[tid + 256]  = e1 * inv;
  wr[tid + 512]  = e2 * inv;
  wr[tid + 768]  = e3 * inv;
}

// ---- K2: QKV GEMM, frag-major operands (coalesced 2KB loads) + pv atomics --
__global__ __launch_bounds__(256) void k_qkv(
    const short* __restrict__ xf, const short* __restrict__ Wtf,
    const float* __restrict__ Ww,
    short* __restrict__ Qf, short* __restrict__ Kf, short* __restrict__ Vf,
    float* __restrict__ pv)
{
  int tid = threadIdx.x;
  int w = tid >> 6, l = tid & 63, H = l >> 5, li = l & 31;
  int bid = blockIdx.x;
  int cb = bid % 12, mb = bid / 12;
  int m0 = mb * 64 + (w & 1) * 32;
  int c0 = cb * 64 + (w >> 1) * 32;
  int mat = c0 >> 8, mc = c0 & 255;
  const short* Apf = xf + ((size_t)((m0 >> 5) * 16)) * 512 + li * 16 + 8 * H;
  const short* Bpf = Wtf + (size_t)mat * 65536
                   + ((size_t)((mc >> 5) * 16)) * 512 + li * 16 + 8 * H;
  f16v acc = {};
#pragma unroll
  for (int kc = 0; kc < 16; ++kc) {
    s8v af = *(const s8v*)(Apf + kc * 512);
    s8v bf = *(const s8v*)(Bpf + kc * 512);
    acc = __builtin_amdgcn_mfma_f32_32x32x16_bf16(af, bf, acc, 0, 0, 0);
  }
  int h = mc >> 5;
  int b = m0 >> 10, nb = m0 & 1023;
  int bh = b * 8 + h;
  if (mat < 2) {
    // Q/K fragment-major: [bh][kc=dh>>4][n][dh&15]
    short* Dst = (mat == 0) ? Qf : Kf;
    size_t base = ((size_t)(bh * 2 + (li >> 4))) * 1024;
#pragma unroll
    for (int r = 0; r < 16; ++r) {
      int crow = (r & 3) + 8 * (r >> 2) + 4 * H;
      Dst[(base + nb + crow) * 16 + (li & 15)] = bf16r(acc[r]);
    }
  } else {
    // V fragment-major: [bh][ks][s][d=li][H''][jj]; j = nb+8*q2+4*H+t
    int ks = nb >> 5;
#pragma unroll
    for (int q2 = 0; q2 < 4; ++q2) {
      uint2 val = make_uint2(pkbf(acc[q2 * 4 + 0], acc[q2 * 4 + 1]),
                             pkbf(acc[q2 * 4 + 2], acc[q2 * 4 + 3]));
      size_t addr = (((size_t)(bh * 32 + ks) * 2 + (q2 >> 1)) * 32 + li) * 16
                  + (q2 & 1) * 8 + 4 * H;
      *(uint2*)(Vf + addr) = val;
    }
    // pv partial (frozen)
    const float* wp = Ww + (size_t)bh * N_ + nb;
    float part = 0.0f;
#pragma unroll
    for (int r = 0; r < 16; ++r) {
      int crow = (r & 3) + 8 * (r >> 2) + 4 * H;
      part = fmaf(wp[crow], acc[r], part);
    }
    atomicAdd(&pv[bh * 32 + li], part);
  }
}

// ---- K3: flash attn (chunk body frozen), frag-major operand loads ----------
__global__ __launch_bounds__(256) void k_attn(
    const short* __restrict__ Qf, const short* __restrict__ Kf,
    const short* __restrict__ Vf, const float* __restrict__ pv,
    const float* __restrict__ gate,
    short* __restrict__ OHfh, short* __restrict__ OHfl)
{
  __shared__ float sml[4][32];
  __shared__ float sO[4][32][33];
  int tid = threadIdx.x;
  int w = tid >> 6, l = tid & 63, H = l >> 5, li = l & 31;
  int bid = blockIdx.x;
  int bh = (bid & 7) * 4 + (bid >> 8);   // 4 bh per XCD -> K/V L2-resident
  int qb = (bid >> 3) & 31;
  int n0 = qb * 32;

  const short* Qpf = Qf + ((size_t)(bh * 2) * 1024 + n0 + li) * 16 + 8 * H;
  s8v qf0 = *(const s8v*)(Qpf);
  s8v qf1 = *(const s8v*)(Qpf + 16384);
  const short* Kbf = Kf + ((size_t)(bh * 2) * 1024 + li) * 16 + 8 * H;
  const short* Vbf = Vf + ((size_t)(bh * 32) * 2 * 32) * 16 + li * 16 + H * 8;

  f16v acc = {};
  float lsum = 0.0f;

#pragma unroll 2
  for (int ch = 0; ch < 8; ++ch) {
    int jb = w * 256 + ch * 32;
    int ks = jb >> 5;
    const short* Kp = Kbf + (size_t)jb * 16;
    s8v kf0 = *(const s8v*)(Kp);
    s8v kf1 = *(const s8v*)(Kp + 16384);
    const short* Vp = Vbf + (size_t)(ks * 2) * 512;
    s8v vf0 = *(const s8v*)(Vp);
    s8v vf1 = *(const s8v*)(Vp + 512);

    f16v S = {};
    S = __builtin_amdgcn_mfma_f32_32x32x16_bf16(kf0, qf0, S, 0, 0, 0);
    S = __builtin_amdgcn_mfma_f32_32x32x16_bf16(kf1, qf1, S, 0, 0, 0);

    float p[16];
#pragma unroll
    for (int r = 0; r < 16; ++r) {
      p[r] = __builtin_amdgcn_exp2f(S[r]);   // no max: sigma(S)~1.44, safe
      lsum += p[r];
    }

    unsigned a0 = pkbf(p[0], p[1]),  a1 = pkbf(p[2], p[3]);
    unsigned b0 = pkbf(p[4], p[5]),  b1 = pkbf(p[6], p[7]);
    unsigned c0 = pkbf(p[8], p[9]),  c1 = pkbf(p[10], p[11]);
    unsigned d0 = pkbf(p[12], p[13]), d1 = pkbf(p[14], p[15]);
    unsigned sa0 = __shfl_xor(a0, 32), sa1 = __shfl_xor(a1, 32);
    unsigned sb0 = __shfl_xor(b0, 32), sb1 = __shfl_xor(b1, 32);
    unsigned sc0 = __shfl_xor(c0, 32), sc1 = __shfl_xor(c1, 32);
    unsigned sd0 = __shfl_xor(d0, 32), sd1 = __shfl_xor(d1, 32);
    u4v t0 = { H ? sb0 : a0, H ? sb1 : a1, H ? b0 : sa0, H ? b1 : sa1 };
    u4v t1 = { H ? sd0 : c0, H ? sd1 : c1, H ? d0 : sc0, H ? d1 : sc1 };

    acc = __builtin_amdgcn_mfma_f32_32x32x16_bf16(vf0, __builtin_bit_cast(s8v, t0), acc, 0, 0, 0);
    acc = __builtin_amdgcn_mfma_f32_32x32x16_bf16(vf1, __builtin_bit_cast(s8v, t1), acc, 0, 0, 0);
  }

  lsum += __shfl_xor(lsum, 32);
  if (H == 0) sml[w][li] = lsum;
#pragma unroll
  for (int r = 0; r < 16; ++r) {
    int d = (r & 3) + 8 * (r >> 2) + 4 * H;
    sO[w][d][li] = acc[r];
  }
  __syncthreads();

  // combine (frozen math), write OH fragment-major
  int i = tid >> 3, dq = (tid & 7) * 4;
  float L = sml[0][i] + sml[1][i] + sml[2][i] + sml[3][i];
  int b = bh >> 3, h = bh & 7;
  float gh = 1.0f / (1.0f + __expf(-gate[h]));
  float invL = (1.0f - gh) / L;
  const float4 pvv = *(const float4*)(pv + bh * 32 + dq);
  float o[4] = {
    (sO[0][dq + 0][i] + sO[1][dq + 0][i] + sO[2][dq + 0][i] + sO[3][dq + 0][i]) * invL + gh * pvv.x,
    (sO[0][dq + 1][i] + sO[1][dq + 1][i] + sO[2][dq + 1][i] + sO[3][dq + 1][i]) * invL + gh * pvv.y,
    (sO[0][dq + 2][i] + sO[1][dq + 2][i] + sO[2][dq + 2][i] + sO[3][dq + 2][i]) * invL + gh * pvv.z,
    (sO[0][dq + 3][i] + sO[1][dq + 3][i] + sO[2][dq + 3][i] + sO[3][dq + 3][i]) * invL + gh * pvv.w
  };
  float hi[4], lo[4];
#pragma unroll
  for (int q = 0; q < 4; ++q) {
    hi[q] = bfu(bf16r(o[q]));
    lo[q] = o[q] - hi[q];
  }
  int kc = h * 2 + (dq >> 4);
  int rem = dq & 15;                     // {0,4,8,12}
  size_t addr = ((size_t)((b * 32 + qb) * 16 + kc)) * 512 + i * 16 + rem;
  *(uint2*)(OHfh + addr) = make_uint2(pkbf(hi[0], hi[1]), pkbf(hi[2], hi[3]));
  *(uint2*)(OHfl + addr) = make_uint2(pkbf(lo[0], lo[1]), pkbf(lo[2], lo[3]));
}

// ---- K4: out = (OHhi+OHlo) @ Wo + bo, frag-major operands ------------------
__global__ __launch_bounds__(256) void k_out(
    const short* __restrict__ OHfh, const short* __restrict__ OHfl,
    const short* __restrict__ Wof, const float* __restrict__ bo,
    float* __restrict__ out)
{
  int tid = threadIdx.x;
  int w = tid >> 6, l = tid & 63, H = l >> 5, li = l & 31;
  int bid = blockIdx.x;
  int m0 = (bid >> 2) * 64 + (w & 1) * 32;
  int c0 = (bid & 3) * 64 + (w >> 1) * 32;
  const short* Ahf = OHfh + ((size_t)((m0 >> 5) * 16)) * 512 + li * 16 + 8 * H;
  const short* Alf = OHfl + ((size_t)((m0 >> 5) * 16)) * 512 + li * 16 + 8 * H;
  const short* Bpf = Wof + ((size_t)((c0 >> 5) * 16)) * 512 + li * 16 + 8 * H;
  f16v acc = {};
#pragma unroll
  for (int kc = 0; kc < 16; ++kc) {
    s8v bf = *(const s8v*)(Bpf + kc * 512);
    s8v ah = *(const s8v*)(Ahf + kc * 512);
    s8v al = *(const s8v*)(Alf + kc * 512);
    acc = __builtin_amdgcn_mfma_f32_32x32x16_bf16(ah, bf, acc, 0, 0, 0);
    acc = __builtin_amdgcn_mfma_f32_32x32x16_bf16(al, bf, acc, 0, 0, 0);
  }
  float bias = bo[c0 + li];
#pragma unroll
  for (int r = 0; r < 16; ++r) {
    int crow = (r & 3) + 8 * (r >> 2) + 4 * H;
    out[(size_t)(m0 + crow) * 256 + c0 + li] = acc[r] + bias;
  }
}

// ============================================================================
extern "C" void kernel_launch(void* const* d_in, const int* in_sizes, int n_in,
                              void* d_out, int out_size, void* d_ws, size_t ws_size,
                              hipStream_t stream) {
  const float* x    = (const float*)d_in[0];
  // d_in[1] = deep_semantics: unused by the reference
  const float* pos  = (const float*)d_in[2];
  const float* Wq   = (const float*)d_in[3];
  const float* Wk   = (const float*)d_in[4];
  const float* Wv   = (const float*)d_in[5];
  const float* Wo   = (const float*)d_in[6];
  const float* bo   = (const float*)d_in[7];
  const float* Wp1  = (const float*)d_in[8];
  const float* bp1  = (const float*)d_in[9];
  const float* Wp2  = (const float*)d_in[10];
  const float* bp2  = (const float*)d_in[11];
  const float* Wh   = (const float*)d_in[12];
  // d_in[13] = bh: cancels in softmax over keys
  const float* gate = (const float*)d_in[14];
  float* out = (float*)d_out;

  char* base = (char*)d_ws;
  short* Qf   = (short*)(base);                               // 2MB
  short* Kf   = (short*)(base + (2u << 20));                  // 2MB
  short* Vf   = (short*)(base + (4u << 20));                  // 2MB
  short* OHfh = (short*)(base + (6u << 20));                  // 2MB
  short* OHfl = (short*)(base + (8u << 20));                  // 2MB
  short* xf   = (short*)(base + (10u << 20));                 // 2MB
  short* Wtf  = (short*)(base + (12u << 20));                 // 384KB
  short* Wof  = (short*)(base + (12u << 20) + (384u << 10));  // 128KB
  float* Ww   = (float*)(base + (12u << 20) + (512u << 10));  // 128KB
  float* pv   = (float*)(base + (12u << 20) + (640u << 10));  // 4KB

  k_prep<<<608,  256, 0, stream>>>(Wq, Wk, Wv, Wo, pos, Wp1, bp1, Wp2, bp2, Wh,
                                   x, Wtf, Wof, Ww, xf, pv);
  k_qkv <<<768,  256, 0, stream>>>(xf, Wtf, Ww, Qf, Kf, Vf, pv);
  k_attn<<<1024, 256, 0, stream>>>(Qf, Kf, Vf, pv, gate, OHfh, OHfl);
  k_out <<<256,  256, 0, stream>>>(OHfh, OHfl, Wof, bo, out);
}

// Round 14
// 43.760 us; speedup vs baseline: 8.2288x; 1.0042x over previous
//
#include <hip/hip_runtime.h>
#include <hip/hip_bf16.h>

// ============================================================================
// Round 14: merge of two verified parents. r13's fragment-major layouts
// (43.9us, all kernels frozen) + r12's 8-wave x 128-key attn decomposition
// (passed at 57.74 pre-layout). Mechanism: halve per-wave serial chunk chain
// (8->4), double waves/block (4->8) — retargets the latency regime exposed
// now that transaction count is fixed.
//   X/Q/K/W/OH: [tile][kc][row&31][16];  V: [bh][ks][s][d][H][8]
// Exact algebra (r1-r8): pos branch rank-1 => w[b,h,j]=softmax_j(-s[b,h,j]);
// renorm no-op. bf16 MFMA 32x32x16; C/D col=lane&31, row=(reg&3)+8*(reg>>2)
// +4*(lane>>5). No-max softmax: Wq pre-scaled to exp2 units (sigma~1.44).
// ============================================================================

constexpr int N_ = 1024, PD_ = 16;

typedef short  s8v  __attribute__((ext_vector_type(8)));
typedef float  f16v __attribute__((ext_vector_type(16)));
typedef unsigned u4v __attribute__((ext_vector_type(4)));

__device__ inline unsigned pkbf(float lo, float hi) {
  unsigned r;
  asm("v_cvt_pk_bf16_f32 %0, %1, %2" : "=v"(r) : "v"(lo), "v"(hi));
  return r;
}
__device__ inline short bf16r(float f) {
  unsigned u = __float_as_uint(f);
  u += 0x7fff + ((u >> 16) & 1);
  return (short)(u >> 16);
}
__device__ inline float bfu(short s) {
  return __uint_as_float(((unsigned)(unsigned short)s) << 16);
}

// ---- K1: W^T->frag-major (64 blk) | pos MLP+softmax + pv zero (32 blk) |
//          x->frag-major bf16 (512 blk)  [r13-frozen] ------------------------
__global__ __launch_bounds__(256) void k_prep(
    const float* __restrict__ Wq, const float* __restrict__ Wk,
    const float* __restrict__ Wv, const float* __restrict__ Wo,
    const float* __restrict__ pos, const float* __restrict__ Wp1,
    const float* __restrict__ bp1, const float* __restrict__ Wp2,
    const float* __restrict__ bp2, const float* __restrict__ Wh,
    const float* __restrict__ x,
    short* __restrict__ Wtf, short* __restrict__ Wof, float* __restrict__ Ww,
    short* __restrict__ xf, float* __restrict__ pv)
{
  int bid = blockIdx.x;
  int tid = threadIdx.x;

  if (bid >= 96) {
    size_t idx = ((size_t)(bid - 96) * 256 + tid) * 8;
    int m = (int)(idx >> 8), k0 = (int)(idx & 255);
    const float4* p = (const float4*)(x + idx);
    float4 f0 = p[0], f1 = p[1];
    u4v o = { pkbf(f0.x, f0.y), pkbf(f0.z, f0.w), pkbf(f1.x, f1.y), pkbf(f1.z, f1.w) };
    size_t dst = ((size_t)((m >> 5) * 16 + (k0 >> 4))) * 512 + (m & 31) * 16 + (k0 & 15);
    *(u4v*)(xf + dst) = o;
    return;
  }

  if (bid < 64) {
    __shared__ float tile[64][65];
    int mat = bid >> 4, t = bid & 15;
    int k0t = (t >> 2) * 64, c0t = (t & 3) * 64;
    const float* W = mat == 0 ? Wq : mat == 1 ? Wk : mat == 2 ? Wv : Wo;
    float scale = (mat == 0) ? 0.2550348662f : 1.0f;   // log2(e)/sqrt(32)
#pragma unroll
    for (int i = 0; i < 16; ++i) {
      int e = tid + i * 256;
      int kr = e >> 6, cc = e & 63;
      tile[kr][cc] = W[(size_t)(k0t + kr) * 256 + c0t + cc];
    }
    __syncthreads();
    short* dst = (mat == 3) ? Wof : (Wtf + mat * 65536);
#pragma unroll
    for (int i = 0; i < 16; ++i) {
      int e = tid + i * 256;
      int cr = e >> 6, kk = e & 63;
      int c = c0t + cr, k = k0t + kk;
      size_t a = ((size_t)((c >> 5) * 16 + (k >> 4))) * 512 + (c & 31) * 16 + (k & 15);
      dst[a] = bf16r(tile[kk][cr] * scale);
    }
    return;
  }

  __shared__ float sWp1[256], sbp1[16], sWp2[512], sbp2[32], sWhc[32];
  __shared__ float redm[4], reds[4];
  int bh = bid - 64;
  int b = bh >> 3, h = bh & 7;
  if (tid < 32) pv[bh * 32 + tid] = 0.0f;
  sWp1[tid] = Wp1[tid];
  sWp2[tid] = Wp2[tid];
  sWp2[tid + 256] = Wp2[tid + 256];
  if (tid < 16) sbp1[tid] = bp1[tid];
  if (tid < 32) { sbp2[tid] = bp2[tid]; sWhc[tid] = Wh[tid * 8 + h]; }
  __syncthreads();

  float a[4];
#pragma unroll
  for (int nn = 0; nn < 4; ++nn) {
    int n = nn * 256 + tid;
    const float* prow = pos + (size_t)((b << 10) + n) * PD_;
    float pr[16];
#pragma unroll
    for (int r = 0; r < 16; ++r) pr[r] = prow[r];
    float h1[16];
#pragma unroll
    for (int c = 0; c < 16; ++c) {
      float v = sbp1[c];
#pragma unroll
      for (int r = 0; r < 16; ++r) v = fmaf(pr[r], sWp1[r * 16 + c], v);
      h1[c] = fmaxf(v, 0.0f);
    }
    float s = 0.0f;
#pragma unroll
    for (int d = 0; d < 32; ++d) {
      float v = sbp2[d];
#pragma unroll
      for (int c = 0; c < 16; ++c) v = fmaf(h1[c], sWp2[c * 32 + d], v);
      s = fmaf(v, sWhc[d], s);
    }
    a[nn] = -s;   // bh[h] constant over n: cancels
  }
  float m = fmaxf(fmaxf(a[0], a[1]), fmaxf(a[2], a[3]));
#pragma unroll
  for (int off = 32; off >= 1; off >>= 1) m = fmaxf(m, __shfl_xor(m, off));
  if ((tid & 63) == 0) redm[tid >> 6] = m;
  __syncthreads();
  float M = fmaxf(fmaxf(redm[0], redm[1]), fmaxf(redm[2], redm[3]));
  float e0 = __expf(a[0] - M), e1 = __expf(a[1] - M);
  float e2 = __expf(a[2] - M), e3 = __expf(a[3] - M);
  float su = e0 + e1 + e2 + e3;
#pragma unroll
  for (int off = 32; off >= 1; off >>= 1) su += __shfl_xor(su, off);
  if ((tid & 63) == 0) reds[tid >> 6] = su;
  __syncthreads();
  float inv = 1.0f / (reds[0] + reds[1] + reds[2] + reds[3]);
  float* wr = Ww + (size_t)bh * N_;
  wr[tid]        = e0 * inv;
  wr[tid + 256]  = e1 * inv;
  wr[tid + 512]  = e2 * inv;
  wr[tid + 768]  = e3 * inv;
}

// ---- K2: QKV GEMM, frag-major operands + pv atomics  [r13-frozen] ----------
__global__ __launch_bounds__(256) void k_qkv(
    const short* __restrict__ xf, const short* __restrict__ Wtf,
    const float* __restrict__ Ww,
    short* __restrict__ Qf, short* __restrict__ Kf, short* __restrict__ Vf,
    float* __restrict__ pv)
{
  int tid = threadIdx.x;
  int w = tid >> 6, l = tid & 63, H = l >> 5, li = l & 31;
  int bid = blockIdx.x;
  int cb = bid % 12, mb = bid / 12;
  int m0 = mb * 64 + (w & 1) * 32;
  int c0 = cb * 64 + (w >> 1) * 32;
  int mat = c0 >> 8, mc = c0 & 255;
  const short* Apf = xf + ((size_t)((m0 >> 5) * 16)) * 512 + li * 16 + 8 * H;
  const short* Bpf = Wtf + (size_t)mat * 65536
                   + ((size_t)((mc >> 5) * 16)) * 512 + li * 16 + 8 * H;
  f16v acc = {};
#pragma unroll
  for (int kc = 0; kc < 16; ++kc) {
    s8v af = *(const s8v*)(Apf + kc * 512);
    s8v bf = *(const s8v*)(Bpf + kc * 512);
    acc = __builtin_amdgcn_mfma_f32_32x32x16_bf16(af, bf, acc, 0, 0, 0);
  }
  int h = mc >> 5;
  int b = m0 >> 10, nb = m0 & 1023;
  int bh = b * 8 + h;
  if (mat < 2) {
    short* Dst = (mat == 0) ? Qf : Kf;
    size_t base = ((size_t)(bh * 2 + (li >> 4))) * 1024;
#pragma unroll
    for (int r = 0; r < 16; ++r) {
      int crow = (r & 3) + 8 * (r >> 2) + 4 * H;
      Dst[(base + nb + crow) * 16 + (li & 15)] = bf16r(acc[r]);
    }
  } else {
    int ks = nb >> 5;
#pragma unroll
    for (int q2 = 0; q2 < 4; ++q2) {
      uint2 val = make_uint2(pkbf(acc[q2 * 4 + 0], acc[q2 * 4 + 1]),
                             pkbf(acc[q2 * 4 + 2], acc[q2 * 4 + 3]));
      size_t addr = (((size_t)(bh * 32 + ks) * 2 + (q2 >> 1)) * 32 + li) * 16
                  + (q2 & 1) * 8 + 4 * H;
      *(uint2*)(Vf + addr) = val;
    }
    const float* wp = Ww + (size_t)bh * N_ + nb;
    float part = 0.0f;
#pragma unroll
    for (int r = 0; r < 16; ++r) {
      int crow = (r & 3) + 8 * (r >> 2) + 4 * H;
      part = fmaf(wp[crow], acc[r], part);
    }
    atomicAdd(&pv[bh * 32 + li], part);
  }
}

// ---- K3: flash attn, 8 waves x 128 keys (r12 decomposition) on r13 layouts -
__global__ __launch_bounds__(512) void k_attn(
    const short* __restrict__ Qf, const short* __restrict__ Kf,
    const short* __restrict__ Vf, const float* __restrict__ pv,
    const float* __restrict__ gate,
    short* __restrict__ OHfh, short* __restrict__ OHfl)
{
  __shared__ float sml[8][32];
  __shared__ float sO[8][32][33];
  int tid = threadIdx.x;
  int w = tid >> 6, l = tid & 63, H = l >> 5, li = l & 31;   // w in 0..7
  int bid = blockIdx.x;
  int bh = (bid & 7) * 4 + (bid >> 8);   // 4 bh per XCD -> K/V L2-resident
  int qb = (bid >> 3) & 31;
  int n0 = qb * 32;

  const short* Qpf = Qf + ((size_t)(bh * 2) * 1024 + n0 + li) * 16 + 8 * H;
  s8v qf0 = *(const s8v*)(Qpf);
  s8v qf1 = *(const s8v*)(Qpf + 16384);
  const short* Kbf = Kf + ((size_t)(bh * 2) * 1024 + li) * 16 + 8 * H;
  const short* Vbf = Vf + ((size_t)(bh * 32) * 2 * 32) * 16 + li * 16 + H * 8;

  f16v acc = {};
  float lsum = 0.0f;

#pragma unroll 2
  for (int ch = 0; ch < 4; ++ch) {
    int jb = w * 128 + ch * 32;
    int ks = jb >> 5;
    const short* Kp = Kbf + (size_t)jb * 16;
    s8v kf0 = *(const s8v*)(Kp);
    s8v kf1 = *(const s8v*)(Kp + 16384);
    const short* Vp = Vbf + (size_t)(ks * 2) * 512;
    s8v vf0 = *(const s8v*)(Vp);
    s8v vf1 = *(const s8v*)(Vp + 512);

    f16v S = {};
    S = __builtin_amdgcn_mfma_f32_32x32x16_bf16(kf0, qf0, S, 0, 0, 0);
    S = __builtin_amdgcn_mfma_f32_32x32x16_bf16(kf1, qf1, S, 0, 0, 0);

    float p[16];
#pragma unroll
    for (int r = 0; r < 16; ++r) {
      p[r] = __builtin_amdgcn_exp2f(S[r]);   // no max: sigma(S)~1.44, safe
      lsum += p[r];
    }

    unsigned a0 = pkbf(p[0], p[1]),  a1 = pkbf(p[2], p[3]);
    unsigned b0 = pkbf(p[4], p[5]),  b1 = pkbf(p[6], p[7]);
    unsigned c0 = pkbf(p[8], p[9]),  c1 = pkbf(p[10], p[11]);
    unsigned d0 = pkbf(p[12], p[13]), d1 = pkbf(p[14], p[15]);
    unsigned sa0 = __shfl_xor(a0, 32), sa1 = __shfl_xor(a1, 32);
    unsigned sb0 = __shfl_xor(b0, 32), sb1 = __shfl_xor(b1, 32);
    unsigned sc0 = __shfl_xor(c0, 32), sc1 = __shfl_xor(c1, 32);
    unsigned sd0 = __shfl_xor(d0, 32), sd1 = __shfl_xor(d1, 32);
    u4v t0 = { H ? sb0 : a0, H ? sb1 : a1, H ? b0 : sa0, H ? b1 : sa1 };
    u4v t1 = { H ? sd0 : c0, H ? sd1 : c1, H ? d0 : sc0, H ? d1 : sc1 };

    acc = __builtin_amdgcn_mfma_f32_32x32x16_bf16(vf0, __builtin_bit_cast(s8v, t0), acc, 0, 0, 0);
    acc = __builtin_amdgcn_mfma_f32_32x32x16_bf16(vf1, __builtin_bit_cast(s8v, t1), acc, 0, 0, 0);
  }

  lsum += __shfl_xor(lsum, 32);
  if (H == 0) sml[w][li] = lsum;
#pragma unroll
  for (int r = 0; r < 16; ++r) {
    int d = (r & 3) + 8 * (r >> 2) + 4 * H;
    sO[w][d][li] = acc[r];
  }
  __syncthreads();

  if (tid < 256) {
    int i = tid >> 3, dq = (tid & 7) * 4;
    float L = sml[0][i] + sml[1][i] + sml[2][i] + sml[3][i]
            + sml[4][i] + sml[5][i] + sml[6][i] + sml[7][i];
    int b = bh >> 3, h = bh & 7;
    float gh = 1.0f / (1.0f + __expf(-gate[h]));
    float invL = (1.0f - gh) / L;
    const float4 pvv = *(const float4*)(pv + bh * 32 + dq);
    float o[4];
#pragma unroll
    for (int q = 0; q < 4; ++q) {
      o[q] = (sO[0][dq + q][i] + sO[1][dq + q][i] + sO[2][dq + q][i] + sO[3][dq + q][i]
            + sO[4][dq + q][i] + sO[5][dq + q][i] + sO[6][dq + q][i] + sO[7][dq + q][i]) * invL;
    }
    o[0] += gh * pvv.x; o[1] += gh * pvv.y; o[2] += gh * pvv.z; o[3] += gh * pvv.w;
    float hi[4], lo[4];
#pragma unroll
    for (int q = 0; q < 4; ++q) {
      hi[q] = bfu(bf16r(o[q]));
      lo[q] = o[q] - hi[q];
    }
    int kc = h * 2 + (dq >> 4);
    int rem = dq & 15;                     // {0,4,8,12}
    size_t addr = ((size_t)((b * 32 + qb) * 16 + kc)) * 512 + i * 16 + rem;
    *(uint2*)(OHfh + addr) = make_uint2(pkbf(hi[0], hi[1]), pkbf(hi[2], hi[3]));
    *(uint2*)(OHfl + addr) = make_uint2(pkbf(lo[0], lo[1]), pkbf(lo[2], lo[3]));
  }
}

// ---- K4: out = (OHhi+OHlo) @ Wo + bo, frag-major operands  [r13-frozen] ----
__global__ __launch_bounds__(256) void k_out(
    const short* __restrict__ OHfh, const short* __restrict__ OHfl,
    const short* __restrict__ Wof, const float* __restrict__ bo,
    float* __restrict__ out)
{
  int tid = threadIdx.x;
  int w = tid >> 6, l = tid & 63, H = l >> 5, li = l & 31;
  int bid = blockIdx.x;
  int m0 = (bid >> 2) * 64 + (w & 1) * 32;
  int c0 = (bid & 3) * 64 + (w >> 1) * 32;
  const short* Ahf = OHfh + ((size_t)((m0 >> 5) * 16)) * 512 + li * 16 + 8 * H;
  const short* Alf = OHfl + ((size_t)((m0 >> 5) * 16)) * 512 + li * 16 + 8 * H;
  const short* Bpf = Wof + ((size_t)((c0 >> 5) * 16)) * 512 + li * 16 + 8 * H;
  f16v acc = {};
#pragma unroll
  for (int kc = 0; kc < 16; ++kc) {
    s8v bf = *(const s8v*)(Bpf + kc * 512);
    s8v ah = *(const s8v*)(Ahf + kc * 512);
    s8v al = *(const s8v*)(Alf + kc * 512);
    acc = __builtin_amdgcn_mfma_f32_32x32x16_bf16(ah, bf, acc, 0, 0, 0);
    acc = __builtin_amdgcn_mfma_f32_32x32x16_bf16(al, bf, acc, 0, 0, 0);
  }
  float bias = bo[c0 + li];
#pragma unroll
  for (int r = 0; r < 16; ++r) {
    int crow = (r & 3) + 8 * (r >> 2) + 4 * H;
    out[(size_t)(m0 + crow) * 256 + c0 + li] = acc[r] + bias;
  }
}

// ============================================================================
extern "C" void kernel_launch(void* const* d_in, const int* in_sizes, int n_in,
                              void* d_out, int out_size, void* d_ws, size_t ws_size,
                              hipStream_t stream) {
  const float* x    = (const float*)d_in[0];
  // d_in[1] = deep_semantics: unused by the reference
  const float* pos  = (const float*)d_in[2];
  const float* Wq   = (const float*)d_in[3];
  const float* Wk   = (const float*)d_in[4];
  const float* Wv   = (const float*)d_in[5];
  const float* Wo   = (const float*)d_in[6];
  const float* bo   = (const float*)d_in[7];
  const float* Wp1  = (const float*)d_in[8];
  const float* bp1  = (const float*)d_in[9];
  const float* Wp2  = (const float*)d_in[10];
  const float* bp2  = (const float*)d_in[11];
  const float* Wh   = (const float*)d_in[12];
  // d_in[13] = bh: cancels in softmax over keys
  const float* gate = (const float*)d_in[14];
  float* out = (float*)d_out;

  char* base = (char*)d_ws;
  short* Qf   = (short*)(base);                               // 2MB
  short* Kf   = (short*)(base + (2u << 20));                  // 2MB
  short* Vf   = (short*)(base + (4u << 20));                  // 2MB
  short* OHfh = (short*)(base + (6u << 20));                  // 2MB
  short* OHfl = (short*)(base + (8u << 20));                  // 2MB
  short* xf   = (short*)(base + (10u << 20));                 // 2MB
  short* Wtf  = (short*)(base + (12u << 20));                 // 384KB
  short* Wof  = (short*)(base + (12u << 20) + (384u << 10));  // 128KB
  float* Ww   = (float*)(base + (12u << 20) + (512u << 10));  // 128KB
  float* pv   = (float*)(base + (12u << 20) + (640u << 10));  // 4KB

  k_prep<<<608,  256, 0, stream>>>(Wq, Wk, Wv, Wo, pos, Wp1, bp1, Wp2, bp2, Wh,
                                   x, Wtf, Wof, Ww, xf, pv);
  k_qkv <<<768,  256, 0, stream>>>(xf, Wtf, Ww, Qf, Kf, Vf, pv);
  k_attn<<<1024, 512, 0, stream>>>(Qf, Kf, Vf, pv, gate, OHfh, OHfl);
  k_out <<<256,  256, 0, stream>>>(OHfh, OHfl, Wof, bo, out);
}